// Round 4
// baseline (25910.742 us; speedup 1.0000x reference)
//
#include <hip/hip_runtime.h>

// ---------------- problem constants ----------------
// B=512, T=128, H=512, ZT=64, GRU_IN=579
// 256 wgs = 16 groups (32 batch rows) x 16 slices (32 hidden units = 96 gate cols)
// block = 512 threads (8 waves, 2/SIMD). GEMMs are k-split: wave w owns k in
// [64w,64w+64), lane owns one unit (3 gate cols), acc[16 rows][3]; partials
// reduced via LDS ds_add_f32 into G buffers. B weights gate-major k-tiled ->
// each B load is a lane-contiguous 512B burst, read ONCE per CU per step.

// ---- ws layout (float element offsets) ----
#define OFF_HID    0u        // [512][512]
#define OFF_BASE   262144u   // [512][512] baseline
#define OFF_WHH0P  524288u   // [16][128 k4][3 gate][32 u][4 ki] Whh0
#define OFF_WIH1P  1310720u  // same, Wih1
#define OFF_WHH1P  2097152u  // same, Whh1
#define OFF_WMIDP  2883584u  // [16][96][512] Wih0 rows 64..575 (for gi0_kernel)
#define OFF_WTOPP  3670016u  // [16][16 k4][3][32][4] Wih0 rows 0..63
#define OFF_WTS    3768320u  // [16][96] Wih0 row 576 (c = 3u+gate)
#define OFF_WIRR   3769856u  // [16][2][96] Wih0 rows 577,578
#define OFF_GI0S   3772928u  // [16][512][96] baseline@Wmid + bih0
#define OFF_H0X    4559360u  // [512][512] h0 exchange
#define OFF_H1X    4821504u  // [512][512] h1 exchange
#define OFF_HWTC   5083648u  // [24][512] W_tc^T
#define OFF_HWHZ   5095936u  // [2][516]  W_hz rows (col 512 = t coef, pad)
#define OFF_HWT0   5097088u  // [6][512]  W_tcat0^T
#define OFF_HWT2   5100160u  // [10][512] W_tcat2^T
#define OFF_HWT4   5105280u  // [4][512]  W_tcat4^T
#define OFF_IRR0   5107328u  // [512][2]
#define OFF_CTR    5108352u  // 16 groups x 32 u32 barrier counters
#define OFF_END    5108864u

// ---- out layout (flat concat, reference return order) ----
#define OUT_SC   0u
#define OUT_SCAT 8192u
#define OUT_TC   20992u
#define OUT_TCAT 1593856u
#define OUT_VM   3035648u
#define OUT_VT   3101184u

__device__ __forceinline__ float sigm(float x) { return 1.0f / (1.0f + expf(-x)); }
__device__ __forceinline__ float gumb(float u) { return -logf(-logf(u + 1e-10f) + 1e-10f); }
__device__ __forceinline__ float dot4(float4 a, float4 b) {
  return fmaf(a.x, b.x, fmaf(a.y, b.y, fmaf(a.z, b.z, a.w * b.w)));
}
__device__ __forceinline__ void astore(float* p, float v) {
  __hip_atomic_store(p, v, __ATOMIC_RELAXED, __HIP_MEMORY_SCOPE_AGENT);
}

// ---------------- weight packing ----------------
__global__ __launch_bounds__(256) void pack_kernel(
    const float* __restrict__ Wih0, const float* __restrict__ Whh0,
    const float* __restrict__ Wih1, const float* __restrict__ Whh1,
    const float* __restrict__ W_tc, const float* __restrict__ W_hz,
    const float* __restrict__ W_tcat0, const float* __restrict__ W_tcat2,
    const float* __restrict__ W_tcat4, float* __restrict__ ws) {
  int idx = blockIdx.x * 256 + threadIdx.x;
  if (idx < 3145728) {
    int m = idx / 786432, r = idx % 786432;
    int s = r / 49152, t = r % 49152;
    if (m < 3) {
      // gate-major k-tiled: [k4][gate][unit][ki]
      int k4 = t / 384, rem = t % 384;
      int j = rem >> 7, u = (rem >> 2) & 31, ki = rem & 3;
      int k = 4 * k4 + ki;
      int col = j * 512 + s * 32 + u;
      const float* M = (m == 0) ? Whh0 : (m == 1) ? Wih1 : Whh1;
      unsigned dst = (m == 0) ? OFF_WHH0P : (m == 1) ? OFF_WIH1P : OFF_WHH1P;
      ws[dst + (unsigned)r] = M[k * 1536 + col];
    } else {
      int c = t / 512, k = t % 512;
      int col = (c % 3) * 512 + s * 32 + c / 3;
      ws[OFF_WMIDP + (unsigned)r] = Wih0[(64 + k) * 1536 + col];
    }
    return;
  }
  idx -= 3145728;
  if (idx < 98304) {  // WTOPP gate-major k-tiled
    int s = idx / 6144, t = idx % 6144;
    int k4 = t / 384, rem = t % 384;
    int j = rem >> 7, u = (rem >> 2) & 31, ki = rem & 3;
    int k = 4 * k4 + ki;
    int col = j * 512 + s * 32 + u;
    ws[OFF_WTOPP + (unsigned)idx] = Wih0[k * 1536 + col];
    return;
  }
  idx -= 98304;
  if (idx < 1536) {
    int s = idx / 96, c = idx % 96;
    ws[OFF_WTS + (unsigned)idx] = Wih0[576 * 1536 + (c % 3) * 512 + s * 32 + (c / 3)];
    return;
  }
  idx -= 1536;
  if (idx < 3072) {
    int s = idx / 192, m = (idx % 192) / 96, c = idx % 96;
    ws[OFF_WIRR + (unsigned)idx] = Wih0[(577 + m) * 1536 + (c % 3) * 512 + s * 32 + (c / 3)];
    return;
  }
  idx -= 3072;
  if (idx < 12288) { int c = idx / 512, k = idx % 512; ws[OFF_HWTC + (unsigned)idx] = W_tc[k * 24 + c]; return; }
  idx -= 12288;
  if (idx < 1032) {
    int c = idx / 516, j = idx % 516;
    ws[OFF_HWHZ + (unsigned)idx] = (j < 513) ? W_hz[c * 513 + j] : 0.0f;
    return;
  }
  idx -= 1032;
  if (idx < 3072) { int c = idx / 512, k = idx % 512; ws[OFF_HWT0 + (unsigned)idx] = W_tcat0[k * 6 + c]; return; }
  idx -= 3072;
  if (idx < 5120) { int c = idx / 512, k = idx % 512; ws[OFF_HWT2 + (unsigned)idx] = W_tcat2[k * 10 + c]; return; }
  idx -= 5120;
  if (idx < 2048) { int c = idx / 512, k = idx % 512; ws[OFF_HWT4 + (unsigned)idx] = W_tcat4[k * 4 + c]; }
}

// ---------------- static MLP ----------------
template <int K>
__global__ __launch_bounds__(256) void mlp_kernel(
    const float* __restrict__ X, const float* __restrict__ Wm,
    const float* __restrict__ bias, float* __restrict__ Y) {
  __shared__ float Xs[4][K];
  const int rt = blockIdx.x, tid = threadIdx.x;
  for (int i = tid; i < 4 * K; i += 256) Xs[i / K][i % K] = X[(rt * 4 + i / K) * K + (i % K)];
  __syncthreads();
  float acc[4][2] = {};
  const int c0 = tid, c1 = tid + 256;
  for (int k = 0; k < K; ++k) {
    float w0 = Wm[k * 512 + c0], w1 = Wm[k * 512 + c1];
#pragma unroll
    for (int r = 0; r < 4; ++r) {
      acc[r][0] = fmaf(Xs[r][k], w0, acc[r][0]);
      acc[r][1] = fmaf(Xs[r][k], w1, acc[r][1]);
    }
  }
#pragma unroll
  for (int r = 0; r < 4; ++r) {
    Y[(rt * 4 + r) * 512 + c0] = fmaxf(acc[r][0] + bias[c0], 0.0f);
    Y[(rt * 4 + r) * 512 + c1] = fmaxf(acc[r][1] + bias[c1], 0.0f);
  }
}

// ---------------- gi0 static part ----------------
__global__ __launch_bounds__(256) void gi0_kernel(
    const float* __restrict__ baseline, const float* __restrict__ WmidP,
    const float* __restrict__ bih0, float* __restrict__ gi0s) {
  __shared__ float As[64][128];
  __shared__ float Bs[96][129];
  const int s = blockIdx.x >> 3, rt = blockIdx.x & 7;
  const int tid = threadIdx.x, cg = tid & 31, rg = tid >> 5;
  float acc[8][3] = {};
  for (int kc = 0; kc < 4; ++kc) {
    for (int i = tid; i < 2048; i += 256) {
      int r = i >> 5, k4 = (i & 31) << 2;
      *(float4*)&As[r][k4] = *(const float4*)&baseline[(rt * 64 + r) * 512 + kc * 128 + k4];
    }
    for (int i = tid; i < 3072; i += 256) {
      int c = i >> 5, k4 = (i & 31) << 2;
      float4 v = *(const float4*)&WmidP[((unsigned)s * 96 + c) * 512 + kc * 128 + k4];
      Bs[c][k4] = v.x; Bs[c][k4 + 1] = v.y; Bs[c][k4 + 2] = v.z; Bs[c][k4 + 3] = v.w;
    }
    __syncthreads();
    for (int kk = 0; kk < 128; ++kk) {
      float b0 = Bs[3 * cg + 0][kk], b1 = Bs[3 * cg + 1][kk], b2 = Bs[3 * cg + 2][kk];
#pragma unroll
      for (int r = 0; r < 8; ++r) {
        float a = As[rg * 8 + r][kk];
        acc[r][0] = fmaf(a, b0, acc[r][0]);
        acc[r][1] = fmaf(a, b1, acc[r][1]);
        acc[r][2] = fmaf(a, b2, acc[r][2]);
      }
    }
    __syncthreads();
  }
#pragma unroll
  for (int r = 0; r < 8; ++r)
#pragma unroll
    for (int j = 0; j < 3; ++j) {
      int c = 3 * cg + j;
      gi0s[((unsigned)s * 512 + rt * 64 + rg * 8 + r) * 96 + c] = acc[r][j] + bih0[j * 512 + s * 32 + cg];
    }
}

// ---------------- static heads ----------------
__device__ void gumbel_write(const float* logits, int w, const float* u, float* dst) {
  float e[12]; float mx = -1e30f;
#pragma unroll
  for (int i = 0; i < 12; ++i) if (i < w) { e[i] = logits[i] + gumb(u[i]); mx = fmaxf(mx, e[i]); }
  float sum = 0.0f;
#pragma unroll
  for (int i = 0; i < 12; ++i) if (i < w) { e[i] = expf(e[i] - mx); sum += e[i]; }
  float inv = 1.0f / sum;
#pragma unroll
  for (int i = 0; i < 12; ++i) if (i < w) dst[i] = e[i] * inv;
}

__global__ __launch_bounds__(64) void static_heads_kernel(
    const float* __restrict__ baseline,
    const float* __restrict__ W_sc, const float* __restrict__ b_sc,
    const float* __restrict__ W_cat0, const float* __restrict__ b_cat0,
    const float* __restrict__ W_cat1, const float* __restrict__ b_cat1,
    const float* __restrict__ W_cat2, const float* __restrict__ b_cat2,
    const float* __restrict__ W_irr, const float* __restrict__ b_irr,
    const float* __restrict__ u_sc0, const float* __restrict__ u_sc1,
    const float* __restrict__ u_sc2, const float* __restrict__ u_irr,
    float* __restrict__ out, float* __restrict__ irr0buf) {
  const int b = blockIdx.x, tid = threadIdx.x;
  __shared__ float br[512];
  __shared__ float dots[48];
  for (int i = tid; i < 512; i += 64) br[i] = baseline[b * 512 + i];
  __syncthreads();
  if (tid < 45) {
    float d = 0.0f;
    if (tid < 16) { for (int k = 0; k < 512; ++k) d = fmaf(br[k], W_sc[k * 16 + tid], d); d += b_sc[tid]; }
    else if (tid < 24) { int c = tid - 16; for (int k = 0; k < 512; ++k) d = fmaf(br[k], W_cat0[k * 8 + c], d); d += b_cat0[c]; }
    else if (tid < 29) { int c = tid - 24; for (int k = 0; k < 512; ++k) d = fmaf(br[k], W_cat1[k * 5 + c], d); d += b_cat1[c]; }
    else if (tid < 41) { int c = tid - 29; for (int k = 0; k < 512; ++k) d = fmaf(br[k], W_cat2[k * 12 + c], d); d += b_cat2[c]; }
    else { int i = tid - 41, j = i >> 1, cls = i & 1;
           for (int k = 0; k < 512; ++k) d = fmaf(br[k], W_irr[j * 1024 + k * 2 + cls], d);
           d += b_irr[j * 2 + cls]; }
    dots[tid] = d;
  }
  __syncthreads();
  if (tid < 16) out[OUT_SC + b * 16 + tid] = sigm(dots[tid]);
  else if (tid == 16) gumbel_write(&dots[16], 8,  u_sc0 + b * 8,  out + OUT_SCAT + b * 25 + 0);
  else if (tid == 17) gumbel_write(&dots[24], 5,  u_sc1 + b * 5,  out + OUT_SCAT + b * 25 + 8);
  else if (tid == 18) gumbel_write(&dots[29], 12, u_sc2 + b * 12, out + OUT_SCAT + b * 25 + 13);
  else if (tid == 19 || tid == 20) {
    int j = tid - 19;
    float e0 = dots[41 + 2 * j] + gumb(u_irr[j * 1024 + b * 2 + 0]);
    float e1 = dots[42 + 2 * j] + gumb(u_irr[j * 1024 + b * 2 + 1]);
    float mx = fmaxf(e0, e1);
    float x0 = expf(e0 - mx), x1 = expf(e1 - mx);
    irr0buf[b * 2 + j] = x1 / (x0 + x1);
  }
}

// ---------------- persistent recurrence kernel ----------------
__global__ __launch_bounds__(512, 2) void recurrence_kernel(
    float* ws, const float* __restrict__ z_temporal, const int* __restrict__ lengths,
    const float* __restrict__ bhh0, const float* __restrict__ bih1, const float* __restrict__ bhh1,
    const float* __restrict__ b_tc, const float* __restrict__ b_hz,
    const float* __restrict__ b_tcat0, const float* __restrict__ b_tcat2,
    const float* __restrict__ b_tcat4,
    const float* __restrict__ u_t0, const float* __restrict__ u_t2,
    const float* __restrict__ u_t4, const float* __restrict__ u_bern,
    float* __restrict__ out) {
  const int tid = threadIdx.x;
  const int s = blockIdx.x & 15;   // slice -> XCD-pinned (round-robin dispatch)
  const int g = blockIdx.x >> 4;   // batch group
  const int b0 = g * 32;
  // cell/epilogue role
  const int cg = tid & 31;
  const int rg = tid >> 5;         // 0..15 ; rows 2rg, 2rg+1
  const int jglob = s * 32 + cg;
  // gemm role (k-split)
  const int lane = tid & 63, wv = tid >> 6;   // wave 0..7: k-chunk [64wv,64wv+64)
  const int u = lane & 31;                    // unit -> gate cols 3u..3u+2
  const int hh = lane >> 5;                   // row half: rows 16hh..16hh+15
  // heads role
  const int hrow = tid >> 4, kp = tid & 15;

  __shared__ __align__(16) float A0[32 * 512];   // 64KB staged h0
  __shared__ __align__(16) float A1[32 * 512];   // 64KB staged h1
  __shared__ __align__(16) float G[2][3072];     // 24KB gate partial sums (Gi,Gh)
  __shared__ float irr_l[32][2];

  float* Gi = G[0];
  float* Gh = G[1];
  float* h0x = ws + OFF_H0X;
  float* h1x = ws + OFF_H1X;
  unsigned* ctr = ((unsigned*)(ws + OFF_CTR)) + g * 32;

  const float* WpA = ws + OFF_WHH0P + (unsigned)s * 49152;
  const float* WpI = ws + OFF_WIH1P + (unsigned)s * 49152;
  const float* WpH = ws + OFF_WHH1P + (unsigned)s * 49152;
  const float* WpT = ws + OFF_WTOPP + (unsigned)s * 6144;

  // per-thread epilogue constants
  const int c0 = 3 * cg;
  const float* wtsp  = ws + OFF_WTS + s * 96;
  const float* wirrp = ws + OFF_WIRR + s * 192;
  const float* gi0p  = ws + OFF_GI0S + ((unsigned)s * 512 + b0) * 96;
  float wts0 = wtsp[c0], wts1 = wtsp[c0 + 1], wts2 = wtsp[c0 + 2];
  float wi00 = wirrp[c0], wi01 = wirrp[c0 + 1], wi02 = wirrp[c0 + 2];
  float wi10 = wirrp[96 + c0], wi11 = wirrp[96 + c0 + 1], wi12 = wirrp[96 + c0 + 2];
  float g0s[2][3];
#pragma unroll
  for (int r = 0; r < 2; ++r)
#pragma unroll
    for (int j = 0; j < 3; ++j) g0s[r][j] = gi0p[(2 * rg + r) * 96 + c0 + j];
  float bh0r = bhh0[jglob], bh0z = bhh0[512 + jglob], bh0n = bhh0[1024 + jglob];
  float bi1r = bih1[jglob], bi1z = bih1[512 + jglob], bi1n = bih1[1024 + jglob];
  float bh1r = bhh1[jglob], bh1z = bhh1[512 + jglob], bh1n = bhh1[1024 + jglob];
  float bhz0 = b_hz[0], bhz1 = b_hz[1];

  // init
  for (int i = tid; i < 32 * 512; i += 512) { A0[i] = 0.0f; A1[i] = 0.0f; }
  if (tid < 64) irr_l[tid >> 1][tid & 1] = ws[OFF_IRR0 + (b0 + (tid >> 1)) * 2 + (tid & 1)];
  __syncthreads();

  unsigned bar = 0;
  auto gbar = [&]() {
    __builtin_amdgcn_s_waitcnt(0);
    __syncthreads();
    if (tid == 0) {
      bar += 16;
      __hip_atomic_fetch_add(ctr, 1u, __ATOMIC_RELEASE, __HIP_MEMORY_SCOPE_AGENT);
      while (__hip_atomic_load(ctr, __ATOMIC_RELAXED, __HIP_MEMORY_SCOPE_AGENT) < bar)
        __builtin_amdgcn_s_sleep(1);
    }
    __syncthreads();
    __asm__ __volatile__("" ::: "memory");
  };

  float4 sv[8];  // h staging registers (32 rows x 512 cols / 512 threads)
  auto stage_issue = [&](const float* src) {
#pragma unroll
    for (int j = 0; j < 8; ++j) {
      int slot = j * 512 + tid;
      asm volatile("global_load_dwordx4 %0, %1, off sc1"
                   : "=v"(sv[j]) : "v"(src + (slot >> 7) * 512 + ((slot & 127) << 2)));
    }
  };
  auto stage_finish = [&](float* dstLDS) {
    asm volatile("s_waitcnt vmcnt(0)" ::: "memory");
#pragma unroll
    for (int j = 0; j < 8; ++j) {
      int slot = j * 512 + tid;
      *(float4*)(dstLDS + (slot >> 7) * 512 + ((slot & 127) << 2)) = sv[j];
    }
    __syncthreads();
  };

  auto zeroG = [&]() {
    float4* gz = (float4*)&G[0][0];
    gz[tid] = float4{0, 0, 0, 0};
    gz[tid + 512] = float4{0, 0, 0, 0};
    gz[tid + 1024] = float4{0, 0, 0, 0};
  };

  // k-split K512 gemm: this wave's k-chunk, acc[16 rows][3 gates]
  auto gemmKS = [&](const float* A, const float* Bp, float (&acc)[16][3]) {
    const float* bp = Bp + (unsigned)wv * 6144 + 4 * u;
    const float* ap = A + hh * (16 * 512) + wv * 64;
    float4 nb0 = *(const float4*)(bp);
    float4 nb1 = *(const float4*)(bp + 128);
    float4 nb2 = *(const float4*)(bp + 256);
    for (int k4 = 0; k4 < 16; ++k4) {
      float4 w0 = nb0, w1 = nb1, w2 = nb2;
      if (k4 < 15) {
        const float* p = bp + (k4 + 1) * 384;
        nb0 = *(const float4*)(p);
        nb1 = *(const float4*)(p + 128);
        nb2 = *(const float4*)(p + 256);
      }
      const float* w0a = (const float*)&w0;
      const float* w1a = (const float*)&w1;
      const float* w2a = (const float*)&w2;
      const float* a0 = ap + k4 * 4;
#pragma unroll
      for (int rr = 0; rr < 16; ++rr) {
        float4 av = *(const float4*)(a0 + rr * 512);
        const float* aa = (const float*)&av;
#pragma unroll
        for (int i = 0; i < 4; ++i) {
          acc[rr][0] = fmaf(aa[i], w0a[i], acc[rr][0]);
          acc[rr][1] = fmaf(aa[i], w1a[i], acc[rr][1]);
          acc[rr][2] = fmaf(aa[i], w2a[i], acc[rr][2]);
        }
      }
    }
  };

  // z gemm: k-chunk 8 per wave, A straight from global
  auto gemmZ = [&](int t, float (&acc)[16][3]) {
    const float* bp = WpT + wv * 2 * 384 + 4 * u;
#pragma unroll
    for (int k4 = 0; k4 < 2; ++k4) {
      const float* p = bp + k4 * 384;
      float4 w0 = *(const float4*)(p);
      float4 w1 = *(const float4*)(p + 128);
      float4 w2 = *(const float4*)(p + 256);
      const float* w0a = (const float*)&w0;
      const float* w1a = (const float*)&w1;
      const float* w2a = (const float*)&w2;
#pragma unroll
      for (int rr = 0; rr < 16; ++rr) {
        int row = b0 + hh * 16 + rr;
        float4 zv = *(const float4*)(z_temporal + ((unsigned)row * 128 + t) * 64 + wv * 8 + k4 * 4);
        const float* aa = (const float*)&zv;
#pragma unroll
        for (int i = 0; i < 4; ++i) {
          acc[rr][0] = fmaf(aa[i], w0a[i], acc[rr][0]);
          acc[rr][1] = fmaf(aa[i], w1a[i], acc[rr][1]);
          acc[rr][2] = fmaf(aa[i], w2a[i], acc[rr][2]);
        }
      }
    }
  };

  auto reduceG = [&](float* Gbuf, float (&acc)[16][3]) {
#pragma unroll
    for (int rr = 0; rr < 16; ++rr) {
      float* gp = Gbuf + (hh * 16 + rr) * 96 + 3 * u;
      unsafeAtomicAdd(gp + 0, acc[rr][0]);
      unsafeAtomicAdd(gp + 1, acc[rr][1]);
      unsafeAtomicAdd(gp + 2, acc[rr][2]);
    }
  };

  // heads for step tp (reads A1 = h1_new(tp)); updates irr_l; writes outputs
  auto do_heads = [&](int tp) {
    const float tsp = (float)tp * (1.0f / 127.0f);
    const float* Ar = A1 + hrow * 512;
    {
      const float* hz = ws + OFF_HWHZ;
      float d0 = 0.0f, d1 = 0.0f;
#pragma unroll
      for (int i = 0; i < 8; ++i) {
        int k = kp * 4 + 64 * i;
        float4 x = *(const float4*)(Ar + k);
        d0 += dot4(x, *(const float4*)(hz + k));
        d1 += dot4(x, *(const float4*)(hz + 516 + k));
      }
#pragma unroll
      for (int off = 1; off < 16; off <<= 1) { d0 += __shfl_xor(d0, off, 64); d1 += __shfl_xor(d1, off, 64); }
      if (kp == 0) {
        float h0v = sigm(d0 + tsp * hz[512] + bhz0);
        float h1v = sigm(d1 + tsp * hz[516 + 512] + bhz1);
        float i0 = irr_l[hrow][0], i1 = irr_l[hrow][1];
        const float* ub = u_bern + ((unsigned)tp * 512 + b0 + hrow) * 2;
        irr_l[hrow][0] = fminf(i0 + ((ub[0] < h0v * (1.0f - i0)) ? 1.0f : 0.0f), 1.0f);
        irr_l[hrow][1] = fminf(i1 + ((ub[1] < h1v * (1.0f - i1)) ? 1.0f : 0.0f), 1.0f);
      }
    }
    if (s < 12) {
      const float* wt = ws + OFF_HWTC + (unsigned)(2 * s) * 512;
      float d0 = 0.0f, d1 = 0.0f;
#pragma unroll
      for (int i = 0; i < 8; ++i) {
        int k = kp * 4 + 64 * i;
        float4 x = *(const float4*)(Ar + k);
        d0 += dot4(x, *(const float4*)(wt + k));
        d1 += dot4(x, *(const float4*)(wt + 512 + k));
      }
#pragma unroll
      for (int off = 1; off < 16; off <<= 1) { d0 += __shfl_xor(d0, off, 64); d1 += __shfl_xor(d1, off, 64); }
      if (kp == 0) {
        int brow = b0 + hrow;
        float msk = (tp < lengths[brow]) ? 1.0f : 0.0f;
        float* o = out + OUT_TC + ((unsigned)brow * 128 + tp) * 24 + 2 * s;
        o[0] = sigm(d0 + b_tc[2 * s]) * msk;
        o[1] = sigm(d1 + b_tc[2 * s + 1]) * msk;
      }
    } else if (s == 15) {
      if (kp == 0) {
        int brow = b0 + hrow;
        float msk = (tp < lengths[brow]) ? 1.0f : 0.0f;
        out[OUT_TCAT + ((unsigned)brow * 128 + tp) * 22 + 6]  = irr_l[hrow][0] * msk;
        out[OUT_TCAT + ((unsigned)brow * 128 + tp) * 22 + 17] = irr_l[hrow][1] * msk;
        out[OUT_VM + (unsigned)brow * 128 + tp] = msk;
        out[OUT_VT + (unsigned)brow * 128 + tp] = tsp;
      }
    } else {
      const int w = (s == 12) ? 6 : (s == 13) ? 10 : 4;
      const float* WT = ws + ((s == 12) ? OFF_HWT0 : (s == 13) ? OFF_HWT2 : OFF_HWT4);
      const float* bt = (s == 12) ? b_tcat0 : (s == 13) ? b_tcat2 : b_tcat4;
      const float* ut = (s == 12) ? u_t0 : (s == 13) ? u_t2 : u_t4;
      const int cbase = (s == 12) ? 0 : (s == 13) ? 7 : 18;
      float lg[10];
#pragma unroll
      for (int c = 0; c < 10; ++c) lg[c] = 0.0f;
#pragma unroll
      for (int i = 0; i < 8; ++i) {
        int k = kp * 4 + 64 * i;
        float4 x = *(const float4*)(Ar + k);
        for (int c = 0; c < w; ++c)
          lg[c] += dot4(x, *(const float4*)(WT + (unsigned)c * 512 + k));
      }
      for (int c = 0; c < w; ++c) {
#pragma unroll
        for (int off = 1; off < 16; off <<= 1) lg[c] += __shfl_xor(lg[c], off, 64);
      }
      if (kp == 0) {
        int brow = b0 + hrow;
        float msk = (tp < lengths[brow]) ? 1.0f : 0.0f;
        float e[10], mx = -1e30f;
        for (int c = 0; c < w; ++c) {
          float uu = ut[((unsigned)tp * 512 + brow) * (unsigned)w + c];
          e[c] = lg[c] + bt[c] + gumb(uu); mx = fmaxf(mx, e[c]);
        }
        float sum = 0.0f;
        for (int c = 0; c < w; ++c) { e[c] = expf(e[c] - mx); sum += e[c]; }
        float inv = 1.0f / sum;
        float* o = out + OUT_TCAT + ((unsigned)brow * 128 + tp) * 22 + cbase;
        for (int c = 0; c < w; ++c) o[c] = e[c] * inv * msk;
      }
    }
    __syncthreads();
  };

  for (int t = 0; t < 128; ++t) {
    const float tsv = (float)t * (1.0f / 127.0f);

    // ---- phase 1 ----
    zeroG();                                   // G free since last gbar2
    float accH[16][3] = {};
    gemmKS(A0, WpA, accH);                     // gh0 partials (A0 = h0_prev)
    if (t > 0) {
      stage_finish(A1);                        // h1_new(t-1) -> A1 (syncs inside)
      do_heads(t - 1);                         // reads A1, updates irr_l; ends with sync
    } else {
      __syncthreads();                         // separate zeroG from ds_adds
    }
    reduceG(Gh, accH);
    float accI[16][3] = {};
    gemmZ(t, accI);                            // zt partials (k=8/wave, global A)
    reduceG(Gi, accI);
    __syncthreads();

    // cell0 epilogue (thread = unit cg x rows 2rg,2rg+1)
#pragma unroll
    for (int r = 0; r < 2; ++r) {
      const int lr = 2 * rg + r;
      float i0 = irr_l[lr][0], i1 = irr_l[lr][1];
      const float* gi = Gi + lr * 96 + c0;
      const float* gh = Gh + lr * 96 + c0;
      float gir = gi[0] + g0s[r][0] + tsv * wts0 + i0 * wi00 + i1 * wi10;
      float giz = gi[1] + g0s[r][1] + tsv * wts1 + i0 * wi01 + i1 * wi11;
      float gin = gi[2] + g0s[r][2] + tsv * wts2 + i0 * wi02 + i1 * wi12;
      float rr = sigm(gir + gh[0] + bh0r);
      float zz = sigm(giz + gh[1] + bh0z);
      float nn = tanhf(gin + rr * (gh[2] + bh0n));
      float hp = A0[lr * 512 + jglob];
      astore(h0x + (unsigned)(b0 + lr) * 512 + jglob, (1.0f - zz) * nn + zz * hp);
    }

    // gh1 partials before barrier (A1 = h1_prev resident) to absorb skew
    float accH2[16][3] = {};
    gemmKS(A1, WpH, accH2);
    gbar();

    // ---- phase 2 ----
    zeroG();                                   // G consumed above; gbar separated
    stage_issue(h0x + b0 * 512);
    stage_finish(A0);                          // h0_new -> A0 (sync separates zero/adds)
    float accI2[16][3] = {};
    gemmKS(A0, WpI, accI2);                    // gi1 partials
    reduceG(Gi, accI2);
    reduceG(Gh, accH2);
    __syncthreads();

    // cell1 epilogue
#pragma unroll
    for (int r = 0; r < 2; ++r) {
      const int lr = 2 * rg + r;
      const float* gi = Gi + lr * 96 + c0;
      const float* gh = Gh + lr * 96 + c0;
      float rr = sigm(gi[0] + bi1r + gh[0] + bh1r);
      float zz = sigm(gi[1] + bi1z + gh[1] + bh1z);
      float nn = tanhf(gi[2] + bi1n + rr * (gh[2] + bh1n));
      float hp = A1[lr * 512 + jglob];
      astore(h1x + (unsigned)(b0 + lr) * 512 + jglob, (1.0f - zz) * nn + zz * hp);
    }
    gbar();

    stage_issue(h1x + b0 * 512);               // drained at next step top
  }
  stage_finish(A1);
  do_heads(127);
}

// ---------------- launcher ----------------
extern "C" void kernel_launch(void* const* d_in, const int* in_sizes, int n_in,
                              void* d_out, int out_size, void* d_ws, size_t ws_size,
                              hipStream_t stream) {
  const float* z_static   = (const float*)d_in[0];
  const float* z_temporal = (const float*)d_in[1];
  const int*   lengths    = (const int*)d_in[2];
  const float* Ws1 = (const float*)d_in[3];
  const float* bs1 = (const float*)d_in[4];
  const float* Ws2 = (const float*)d_in[5];
  const float* bs2 = (const float*)d_in[6];
  const float* W_sc = (const float*)d_in[7];
  const float* b_sc = (const float*)d_in[8];
  const float* W_cat0 = (const float*)d_in[9];
  const float* b_cat0 = (const float*)d_in[10];
  const float* W_cat1 = (const float*)d_in[11];
  const float* b_cat1 = (const float*)d_in[12];
  const float* W_cat2 = (const float*)d_in[13];
  const float* b_cat2 = (const float*)d_in[14];
  const float* W_irr = (const float*)d_in[15];
  const float* b_irr = (const float*)d_in[16];
  const float* Wih0 = (const float*)d_in[17];
  const float* Whh0 = (const float*)d_in[18];
  const float* bih0 = (const float*)d_in[19];
  const float* bhh0 = (const float*)d_in[20];
  const float* Wih1 = (const float*)d_in[21];
  const float* Whh1 = (const float*)d_in[22];
  const float* bih1 = (const float*)d_in[23];
  const float* bhh1 = (const float*)d_in[24];
  const float* W_tc = (const float*)d_in[25];
  const float* b_tc = (const float*)d_in[26];
  const float* W_tcat0 = (const float*)d_in[27];
  const float* b_tcat0 = (const float*)d_in[28];
  const float* W_tcat2 = (const float*)d_in[29];
  const float* b_tcat2 = (const float*)d_in[30];
  const float* W_tcat4 = (const float*)d_in[31];
  const float* b_tcat4 = (const float*)d_in[32];
  const float* W_hz = (const float*)d_in[33];
  const float* b_hz = (const float*)d_in[34];
  const float* u_sc0 = (const float*)d_in[35];
  const float* u_sc1 = (const float*)d_in[36];
  const float* u_sc2 = (const float*)d_in[37];
  const float* u_irr = (const float*)d_in[38];
  const float* u_t0 = (const float*)d_in[39];
  const float* u_t2 = (const float*)d_in[40];
  const float* u_t4 = (const float*)d_in[41];
  const float* u_bern = (const float*)d_in[42];

  float* ws = (float*)d_ws;
  float* out = (float*)d_out;

  hipMemsetAsync((void*)(ws + OFF_CTR), 0, (size_t)(OFF_END - OFF_CTR) * sizeof(float), stream);

  pack_kernel<<<12783, 256, 0, stream>>>(Wih0, Whh0, Wih1, Whh1,
      W_tc, W_hz, W_tcat0, W_tcat2, W_tcat4, ws);
  mlp_kernel<128><<<128, 256, 0, stream>>>(z_static, Ws1, bs1, ws + OFF_HID);
  mlp_kernel<512><<<128, 256, 0, stream>>>(ws + OFF_HID, Ws2, bs2, ws + OFF_BASE);
  static_heads_kernel<<<512, 64, 0, stream>>>(ws + OFF_BASE, W_sc, b_sc,
      W_cat0, b_cat0, W_cat1, b_cat1, W_cat2, b_cat2, W_irr, b_irr,
      u_sc0, u_sc1, u_sc2, u_irr, out, ws + OFF_IRR0);
  gi0_kernel<<<128, 256, 0, stream>>>(ws + OFF_BASE, ws + OFF_WMIDP, bih0, ws + OFF_GI0S);
  recurrence_kernel<<<256, 512, 0, stream>>>(ws, z_temporal, lengths,
      bhh0, bih1, bhh1, b_tc, b_hz, b_tcat0, b_tcat2, b_tcat4,
      u_t0, u_t2, u_t4, u_bern, out);
}

// Round 5
// 14607.298 us; speedup vs baseline: 1.7738x; 1.7738x over previous
//
#include <hip/hip_runtime.h>

// ---------------- problem constants ----------------
// B=512, T=128, H=512, ZT=64, GRU_IN=579
// 256 wgs = 16 groups (32 batch rows) x 16 slices (32 hidden units = 96 gate cols)
// block = 512 threads = 8 waves = kh(2 k-halves) x cq(4 col-quarters).
// lane: u8 = lane&7 (unit within quarter), rg8 = lane>>3; lane owns unit 8cq+u8
// and rows {rg8, rg8+8, rg8+16, rg8+24}; acc[4][3]. kh=1 waves write partials
// to LDS (plain stores), kh=0 waves add + compute the GRU cell in-register.
// B gate-major k-tiled, partitioned over (kh,cq) -> read ONCE per CU per step.

// ---- ws layout (float element offsets) ----
#define OFF_HID    0u        // [512][512]
#define OFF_BASE   262144u   // [512][512] baseline
#define OFF_WHH0P  524288u   // [16][128 k4][3 gate][32 u][4 ki] Whh0
#define OFF_WIH1P  1310720u  // same, Wih1
#define OFF_WHH1P  2097152u  // same, Whh1
#define OFF_WMIDP  2883584u  // [16][96][512] Wih0 rows 64..575 (for gi0_kernel)
#define OFF_WTOPP  3670016u  // [16][16 k4][3][32][4] Wih0 rows 0..63
#define OFF_WTS    3768320u  // [16][96] Wih0 row 576 (c = 3u+gate)
#define OFF_WIRR   3769856u  // [16][2][96] Wih0 rows 577,578
#define OFF_GI0S   3772928u  // [16][512][96] baseline@Wmid + bih0
#define OFF_H0X    4559360u  // [512][512] h0 exchange
#define OFF_H1X    4821504u  // [512][512] h1 exchange
#define OFF_HWTC   5083648u  // [24][512] W_tc^T
#define OFF_HWHZ   5095936u  // [2][516]  W_hz rows (col 512 = t coef, pad)
#define OFF_HWT0   5097088u  // [6][512]  W_tcat0^T
#define OFF_HWT2   5100160u  // [10][512] W_tcat2^T
#define OFF_HWT4   5105280u  // [4][512]  W_tcat4^T
#define OFF_IRR0   5107328u  // [512][2]
#define OFF_CTR    5108352u  // 16 groups x 32 u32 barrier counters
#define OFF_END    5108864u

// ---- out layout (flat concat, reference return order) ----
#define OUT_SC   0u
#define OUT_SCAT 8192u
#define OUT_TC   20992u
#define OUT_TCAT 1593856u
#define OUT_VM   3035648u
#define OUT_VT   3101184u

#define AS 516   // A row stride (pad 4): rows spread over bank groups
#define RS 97    // partial-buffer row stride

__device__ __forceinline__ float sigm(float x) { return 1.0f / (1.0f + expf(-x)); }
__device__ __forceinline__ float gumb(float u) { return -logf(-logf(u + 1e-10f) + 1e-10f); }
__device__ __forceinline__ float dot4(float4 a, float4 b) {
  return fmaf(a.x, b.x, fmaf(a.y, b.y, fmaf(a.z, b.z, a.w * b.w)));
}
__device__ __forceinline__ void astore(float* p, float v) {
  __hip_atomic_store(p, v, __ATOMIC_RELAXED, __HIP_MEMORY_SCOPE_AGENT);
}

// ---------------- weight packing ----------------
__global__ __launch_bounds__(256) void pack_kernel(
    const float* __restrict__ Wih0, const float* __restrict__ Whh0,
    const float* __restrict__ Wih1, const float* __restrict__ Whh1,
    const float* __restrict__ W_tc, const float* __restrict__ W_hz,
    const float* __restrict__ W_tcat0, const float* __restrict__ W_tcat2,
    const float* __restrict__ W_tcat4, float* __restrict__ ws) {
  int idx = blockIdx.x * 256 + threadIdx.x;
  if (idx < 3145728) {
    int m = idx / 786432, r = idx % 786432;
    int s = r / 49152, t = r % 49152;
    if (m < 3) {
      // gate-major k-tiled: [k4][gate][unit][ki]
      int k4 = t / 384, rem = t % 384;
      int j = rem >> 7, u = (rem >> 2) & 31, ki = rem & 3;
      int k = 4 * k4 + ki;
      int col = j * 512 + s * 32 + u;
      const float* M = (m == 0) ? Whh0 : (m == 1) ? Wih1 : Whh1;
      unsigned dst = (m == 0) ? OFF_WHH0P : (m == 1) ? OFF_WIH1P : OFF_WHH1P;
      ws[dst + (unsigned)r] = M[k * 1536 + col];
    } else {
      int c = t / 512, k = t % 512;
      int col = (c % 3) * 512 + s * 32 + c / 3;
      ws[OFF_WMIDP + (unsigned)r] = Wih0[(64 + k) * 1536 + col];
    }
    return;
  }
  idx -= 3145728;
  if (idx < 98304) {  // WTOPP gate-major k-tiled
    int s = idx / 6144, t = idx % 6144;
    int k4 = t / 384, rem = t % 384;
    int j = rem >> 7, u = (rem >> 2) & 31, ki = rem & 3;
    int k = 4 * k4 + ki;
    int col = j * 512 + s * 32 + u;
    ws[OFF_WTOPP + (unsigned)idx] = Wih0[k * 1536 + col];
    return;
  }
  idx -= 98304;
  if (idx < 1536) {
    int s = idx / 96, c = idx % 96;
    ws[OFF_WTS + (unsigned)idx] = Wih0[576 * 1536 + (c % 3) * 512 + s * 32 + (c / 3)];
    return;
  }
  idx -= 1536;
  if (idx < 3072) {
    int s = idx / 192, m = (idx % 192) / 96, c = idx % 96;
    ws[OFF_WIRR + (unsigned)idx] = Wih0[(577 + m) * 1536 + (c % 3) * 512 + s * 32 + (c / 3)];
    return;
  }
  idx -= 3072;
  if (idx < 12288) { int c = idx / 512, k = idx % 512; ws[OFF_HWTC + (unsigned)idx] = W_tc[k * 24 + c]; return; }
  idx -= 12288;
  if (idx < 1032) {
    int c = idx / 516, j = idx % 516;
    ws[OFF_HWHZ + (unsigned)idx] = (j < 513) ? W_hz[c * 513 + j] : 0.0f;
    return;
  }
  idx -= 1032;
  if (idx < 3072) { int c = idx / 512, k = idx % 512; ws[OFF_HWT0 + (unsigned)idx] = W_tcat0[k * 6 + c]; return; }
  idx -= 3072;
  if (idx < 5120) { int c = idx / 512, k = idx % 512; ws[OFF_HWT2 + (unsigned)idx] = W_tcat2[k * 10 + c]; return; }
  idx -= 5120;
  if (idx < 2048) { int c = idx / 512, k = idx % 512; ws[OFF_HWT4 + (unsigned)idx] = W_tcat4[k * 4 + c]; }
}

// ---------------- static MLP ----------------
template <int K>
__global__ __launch_bounds__(256) void mlp_kernel(
    const float* __restrict__ X, const float* __restrict__ Wm,
    const float* __restrict__ bias, float* __restrict__ Y) {
  __shared__ float Xs[4][K];
  const int rt = blockIdx.x, tid = threadIdx.x;
  for (int i = tid; i < 4 * K; i += 256) Xs[i / K][i % K] = X[(rt * 4 + i / K) * K + (i % K)];
  __syncthreads();
  float acc[4][2] = {};
  const int c0 = tid, c1 = tid + 256;
  for (int k = 0; k < K; ++k) {
    float w0 = Wm[k * 512 + c0], w1 = Wm[k * 512 + c1];
#pragma unroll
    for (int r = 0; r < 4; ++r) {
      acc[r][0] = fmaf(Xs[r][k], w0, acc[r][0]);
      acc[r][1] = fmaf(Xs[r][k], w1, acc[r][1]);
    }
  }
#pragma unroll
  for (int r = 0; r < 4; ++r) {
    Y[(rt * 4 + r) * 512 + c0] = fmaxf(acc[r][0] + bias[c0], 0.0f);
    Y[(rt * 4 + r) * 512 + c1] = fmaxf(acc[r][1] + bias[c1], 0.0f);
  }
}

// ---------------- gi0 static part ----------------
__global__ __launch_bounds__(256) void gi0_kernel(
    const float* __restrict__ baseline, const float* __restrict__ WmidP,
    const float* __restrict__ bih0, float* __restrict__ gi0s) {
  __shared__ float As[64][128];
  __shared__ float Bs[96][129];
  const int s = blockIdx.x >> 3, rt = blockIdx.x & 7;
  const int tid = threadIdx.x, cg = tid & 31, rg = tid >> 5;
  float acc[8][3] = {};
  for (int kc = 0; kc < 4; ++kc) {
    for (int i = tid; i < 2048; i += 256) {
      int r = i >> 5, k4 = (i & 31) << 2;
      *(float4*)&As[r][k4] = *(const float4*)&baseline[(rt * 64 + r) * 512 + kc * 128 + k4];
    }
    for (int i = tid; i < 3072; i += 256) {
      int c = i >> 5, k4 = (i & 31) << 2;
      float4 v = *(const float4*)&WmidP[((unsigned)s * 96 + c) * 512 + kc * 128 + k4];
      Bs[c][k4] = v.x; Bs[c][k4 + 1] = v.y; Bs[c][k4 + 2] = v.z; Bs[c][k4 + 3] = v.w;
    }
    __syncthreads();
    for (int kk = 0; kk < 128; ++kk) {
      float b0 = Bs[3 * cg + 0][kk], b1 = Bs[3 * cg + 1][kk], b2 = Bs[3 * cg + 2][kk];
#pragma unroll
      for (int r = 0; r < 8; ++r) {
        float a = As[rg * 8 + r][kk];
        acc[r][0] = fmaf(a, b0, acc[r][0]);
        acc[r][1] = fmaf(a, b1, acc[r][1]);
        acc[r][2] = fmaf(a, b2, acc[r][2]);
      }
    }
    __syncthreads();
  }
#pragma unroll
  for (int r = 0; r < 8; ++r)
#pragma unroll
    for (int j = 0; j < 3; ++j) {
      int c = 3 * cg + j;
      gi0s[((unsigned)s * 512 + rt * 64 + rg * 8 + r) * 96 + c] = acc[r][j] + bih0[j * 512 + s * 32 + cg];
    }
}

// ---------------- static heads ----------------
__device__ void gumbel_write(const float* logits, int w, const float* u, float* dst) {
  float e[12]; float mx = -1e30f;
#pragma unroll
  for (int i = 0; i < 12; ++i) if (i < w) { e[i] = logits[i] + gumb(u[i]); mx = fmaxf(mx, e[i]); }
  float sum = 0.0f;
#pragma unroll
  for (int i = 0; i < 12; ++i) if (i < w) { e[i] = expf(e[i] - mx); sum += e[i]; }
  float inv = 1.0f / sum;
#pragma unroll
  for (int i = 0; i < 12; ++i) if (i < w) dst[i] = e[i] * inv;
}

__global__ __launch_bounds__(64) void static_heads_kernel(
    const float* __restrict__ baseline,
    const float* __restrict__ W_sc, const float* __restrict__ b_sc,
    const float* __restrict__ W_cat0, const float* __restrict__ b_cat0,
    const float* __restrict__ W_cat1, const float* __restrict__ b_cat1,
    const float* __restrict__ W_cat2, const float* __restrict__ b_cat2,
    const float* __restrict__ W_irr, const float* __restrict__ b_irr,
    const float* __restrict__ u_sc0, const float* __restrict__ u_sc1,
    const float* __restrict__ u_sc2, const float* __restrict__ u_irr,
    float* __restrict__ out, float* __restrict__ irr0buf) {
  const int b = blockIdx.x, tid = threadIdx.x;
  __shared__ float br[512];
  __shared__ float dots[48];
  for (int i = tid; i < 512; i += 64) br[i] = baseline[b * 512 + i];
  __syncthreads();
  if (tid < 45) {
    float d = 0.0f;
    if (tid < 16) { for (int k = 0; k < 512; ++k) d = fmaf(br[k], W_sc[k * 16 + tid], d); d += b_sc[tid]; }
    else if (tid < 24) { int c = tid - 16; for (int k = 0; k < 512; ++k) d = fmaf(br[k], W_cat0[k * 8 + c], d); d += b_cat0[c]; }
    else if (tid < 29) { int c = tid - 24; for (int k = 0; k < 512; ++k) d = fmaf(br[k], W_cat1[k * 5 + c], d); d += b_cat1[c]; }
    else if (tid < 41) { int c = tid - 29; for (int k = 0; k < 512; ++k) d = fmaf(br[k], W_cat2[k * 12 + c], d); d += b_cat2[c]; }
    else { int i = tid - 41, j = i >> 1, cls = i & 1;
           for (int k = 0; k < 512; ++k) d = fmaf(br[k], W_irr[j * 1024 + k * 2 + cls], d);
           d += b_irr[j * 2 + cls]; }
    dots[tid] = d;
  }
  __syncthreads();
  if (tid < 16) out[OUT_SC + b * 16 + tid] = sigm(dots[tid]);
  else if (tid == 16) gumbel_write(&dots[16], 8,  u_sc0 + b * 8,  out + OUT_SCAT + b * 25 + 0);
  else if (tid == 17) gumbel_write(&dots[24], 5,  u_sc1 + b * 5,  out + OUT_SCAT + b * 25 + 8);
  else if (tid == 18) gumbel_write(&dots[29], 12, u_sc2 + b * 12, out + OUT_SCAT + b * 25 + 13);
  else if (tid == 19 || tid == 20) {
    int j = tid - 19;
    float e0 = dots[41 + 2 * j] + gumb(u_irr[j * 1024 + b * 2 + 0]);
    float e1 = dots[42 + 2 * j] + gumb(u_irr[j * 1024 + b * 2 + 1]);
    float mx = fmaxf(e0, e1);
    float x0 = expf(e0 - mx), x1 = expf(e1 - mx);
    irr0buf[b * 2 + j] = x1 / (x0 + x1);
  }
}

// ---------------- persistent recurrence kernel ----------------
__global__ __launch_bounds__(512, 2) void recurrence_kernel(
    float* ws, const float* __restrict__ z_temporal, const int* __restrict__ lengths,
    const float* __restrict__ bhh0, const float* __restrict__ bih1, const float* __restrict__ bhh1,
    const float* __restrict__ b_tc, const float* __restrict__ b_hz,
    const float* __restrict__ b_tcat0, const float* __restrict__ b_tcat2,
    const float* __restrict__ b_tcat4,
    const float* __restrict__ u_t0, const float* __restrict__ u_t2,
    const float* __restrict__ u_t4, const float* __restrict__ u_bern,
    float* __restrict__ out) {
  const int tid = threadIdx.x;
  const int s = blockIdx.x & 15;   // slice -> XCD-pinned (round-robin dispatch)
  const int g = blockIdx.x >> 4;   // batch group
  const int b0 = g * 32;
  // gemm/cell role
  const int lane = tid & 63, wv = tid >> 6;
  const int kh = wv >> 2;          // k-half [256kh, 256kh+256)
  const int cq = wv & 3;           // col quarter: units [8cq, 8cq+8)
  const int u8 = lane & 7;
  const int rg8 = lane >> 3;       // rows {rg8, rg8+8, rg8+16, rg8+24}
  const int unit = 8 * cq + u8;    // unit within slice
  const int jglob = s * 32 + unit;
  // heads role
  const int hrow = tid >> 4, kp = tid & 15;

  __shared__ __align__(16) float A0[32 * AS];      // staged h0 (pad-4 rows)
  __shared__ __align__(16) float A1[32 * AS];      // staged h1
  __shared__ __align__(16) float Rbuf[2 * 32 * RS];// kh=1 partials (2 gemms)
  __shared__ float irr_l[32][2];

  float* h0x = ws + OFF_H0X;
  float* h1x = ws + OFF_H1X;
  unsigned* ctr = ((unsigned*)(ws + OFF_CTR)) + g * 32;

  const float* WpA = ws + OFF_WHH0P + (unsigned)s * 49152;
  const float* WpI = ws + OFF_WIH1P + (unsigned)s * 49152;
  const float* WpH = ws + OFF_WHH1P + (unsigned)s * 49152;
  const float* WpT = ws + OFF_WTOPP + (unsigned)s * 6144;

  // per-lane cell constants (used by kh==0 lanes; harmless for kh==1)
  const int c0u = 3 * unit;
  const float* wtsp  = ws + OFF_WTS + s * 96;
  const float* wirrp = ws + OFF_WIRR + s * 192;
  const float* gi0p  = ws + OFF_GI0S + ((unsigned)s * 512 + b0) * 96;
  float wts0 = wtsp[c0u], wts1 = wtsp[c0u + 1], wts2 = wtsp[c0u + 2];
  float wi00 = wirrp[c0u], wi01 = wirrp[c0u + 1], wi02 = wirrp[c0u + 2];
  float wi10 = wirrp[96 + c0u], wi11 = wirrp[96 + c0u + 1], wi12 = wirrp[96 + c0u + 2];
  float g0s[4][3];
#pragma unroll
  for (int q = 0; q < 4; ++q)
#pragma unroll
    for (int j = 0; j < 3; ++j) g0s[q][j] = gi0p[(rg8 + 8 * q) * 96 + c0u + j];
  float bh0r = bhh0[jglob], bh0z = bhh0[512 + jglob], bh0n = bhh0[1024 + jglob];
  float bi1r = bih1[jglob], bi1z = bih1[512 + jglob], bi1n = bih1[1024 + jglob];
  float bh1r = bhh1[jglob], bh1z = bhh1[512 + jglob], bh1n = bhh1[1024 + jglob];
  float bhz0 = b_hz[0], bhz1 = b_hz[1];

  // init
  for (int i = tid; i < 32 * AS; i += 512) { A0[i] = 0.0f; A1[i] = 0.0f; }
  if (tid < 64) irr_l[tid >> 1][tid & 1] = ws[OFF_IRR0 + (b0 + (tid >> 1)) * 2 + (tid & 1)];
  __syncthreads();

  unsigned bar = 0;
  auto gbar = [&]() {
    __builtin_amdgcn_s_waitcnt(0);
    __syncthreads();
    if (tid == 0) {
      bar += 16;
      __hip_atomic_fetch_add(ctr, 1u, __ATOMIC_RELEASE, __HIP_MEMORY_SCOPE_AGENT);
      while (__hip_atomic_load(ctr, __ATOMIC_RELAXED, __HIP_MEMORY_SCOPE_AGENT) < bar)
        __builtin_amdgcn_s_sleep(1);
    }
    __syncthreads();
    __asm__ __volatile__("" ::: "memory");
  };

  float4 sv[8];  // h staging registers (32 rows x 512 cols / 512 threads)
  auto stage_issue = [&](const float* src) {
#pragma unroll
    for (int j = 0; j < 8; ++j) {
      int slot = j * 512 + tid;
      asm volatile("global_load_dwordx4 %0, %1, off sc1"
                   : "=v"(sv[j]) : "v"(src + (slot >> 7) * 512 + ((slot & 127) << 2)));
    }
  };
  auto stage_finish = [&](float* dstLDS) {
    asm volatile("s_waitcnt vmcnt(0)" ::: "memory");
#pragma unroll
    for (int j = 0; j < 8; ++j) {
      int slot = j * 512 + tid;
      *(float4*)(dstLDS + (slot >> 7) * AS + ((slot & 127) << 2)) = sv[j];
    }
    __syncthreads();
  };

  // K512 gemm, k-half split: acc[q][gate], rows rg8+8q, unit's 3 gate cols.
  // B read once per block (kh x cq partition), lane-contiguous 128B bursts.
  auto gemmKS = [&](const float* A, const float* Bp, float (&acc)[4][3]) {
    const float* bp = Bp + (unsigned)(kh * 64) * 384 + (unsigned)unit * 4;
    const float* ap = A + (unsigned)rg8 * AS + kh * 256;
#pragma unroll 4
    for (int k4 = 0; k4 < 64; ++k4) {
      const float* p = bp + (unsigned)k4 * 384;
      float4 w0 = *(const float4*)(p);
      float4 w1 = *(const float4*)(p + 128);
      float4 w2 = *(const float4*)(p + 256);
      float4 av[4];
#pragma unroll
      for (int q = 0; q < 4; ++q) av[q] = *(const float4*)(ap + q * (8 * AS) + k4 * 4);
      const float* w0a = (const float*)&w0;
      const float* w1a = (const float*)&w1;
      const float* w2a = (const float*)&w2;
#pragma unroll
      for (int q = 0; q < 4; ++q) {
        const float* aa = (const float*)&av[q];
#pragma unroll
        for (int i = 0; i < 4; ++i) {
          acc[q][0] = fmaf(aa[i], w0a[i], acc[q][0]);
          acc[q][1] = fmaf(aa[i], w1a[i], acc[q][1]);
          acc[q][2] = fmaf(aa[i], w2a[i], acc[q][2]);
        }
      }
    }
  };

  // z gemm (K=64, k-half 32 per kh), A straight from global
  auto gemmZ = [&](int t, float (&acc)[4][3]) {
    const float* bp = WpT + (unsigned)(kh * 8) * 384 + (unsigned)unit * 4;
#pragma unroll 2
    for (int k4 = 0; k4 < 8; ++k4) {
      const float* p = bp + (unsigned)k4 * 384;
      float4 w0 = *(const float4*)(p);
      float4 w1 = *(const float4*)(p + 128);
      float4 w2 = *(const float4*)(p + 256);
      const float* w0a = (const float*)&w0;
      const float* w1a = (const float*)&w1;
      const float* w2a = (const float*)&w2;
#pragma unroll
      for (int q = 0; q < 4; ++q) {
        int row = b0 + rg8 + 8 * q;
        float4 zv = *(const float4*)(z_temporal + ((unsigned)row * 128 + t) * 64 + kh * 32 + k4 * 4);
        const float* aa = (const float*)&zv;
#pragma unroll
        for (int i = 0; i < 4; ++i) {
          acc[q][0] = fmaf(aa[i], w0a[i], acc[q][0]);
          acc[q][1] = fmaf(aa[i], w1a[i], acc[q][1]);
          acc[q][2] = fmaf(aa[i], w2a[i], acc[q][2]);
        }
      }
    }
  };

  // kh=1 writes both gemms' partials; sync; kh=0 adds.
  auto reduce2 = [&](float (&aX)[4][3], float (&aY)[4][3]) {
    if (kh == 1) {
#pragma unroll
      for (int q = 0; q < 4; ++q) {
        int row = rg8 + 8 * q;
        float* p0 = Rbuf + row * RS + c0u;
        float* p1 = Rbuf + 32 * RS + row * RS + c0u;
        p0[0] = aX[q][0]; p0[1] = aX[q][1]; p0[2] = aX[q][2];
        p1[0] = aY[q][0]; p1[1] = aY[q][1]; p1[2] = aY[q][2];
      }
    }
    __syncthreads();
    if (kh == 0) {
#pragma unroll
      for (int q = 0; q < 4; ++q) {
        int row = rg8 + 8 * q;
        const float* p0 = Rbuf + row * RS + c0u;
        const float* p1 = Rbuf + 32 * RS + row * RS + c0u;
        aX[q][0] += p0[0]; aX[q][1] += p0[1]; aX[q][2] += p0[2];
        aY[q][0] += p1[0]; aY[q][1] += p1[1]; aY[q][2] += p1[2];
      }
    }
  };

  // heads for step tp (reads A1 = h1_new(tp)); updates irr_l; writes outputs
  auto do_heads = [&](int tp) {
    const float tsp = (float)tp * (1.0f / 127.0f);
    const float* Ar = A1 + hrow * AS;
    {
      const float* hz = ws + OFF_HWHZ;
      float d0 = 0.0f, d1 = 0.0f;
#pragma unroll
      for (int i = 0; i < 8; ++i) {
        int k = kp * 4 + 64 * i;
        float4 x = *(const float4*)(Ar + k);
        d0 += dot4(x, *(const float4*)(hz + k));
        d1 += dot4(x, *(const float4*)(hz + 516 + k));
      }
#pragma unroll
      for (int off = 1; off < 16; off <<= 1) { d0 += __shfl_xor(d0, off, 64); d1 += __shfl_xor(d1, off, 64); }
      if (kp == 0) {
        float h0v = sigm(d0 + tsp * hz[512] + bhz0);
        float h1v = sigm(d1 + tsp * hz[516 + 512] + bhz1);
        float i0 = irr_l[hrow][0], i1 = irr_l[hrow][1];
        const float* ub = u_bern + ((unsigned)tp * 512 + b0 + hrow) * 2;
        irr_l[hrow][0] = fminf(i0 + ((ub[0] < h0v * (1.0f - i0)) ? 1.0f : 0.0f), 1.0f);
        irr_l[hrow][1] = fminf(i1 + ((ub[1] < h1v * (1.0f - i1)) ? 1.0f : 0.0f), 1.0f);
      }
    }
    if (s < 12) {
      const float* wt = ws + OFF_HWTC + (unsigned)(2 * s) * 512;
      float d0 = 0.0f, d1 = 0.0f;
#pragma unroll
      for (int i = 0; i < 8; ++i) {
        int k = kp * 4 + 64 * i;
        float4 x = *(const float4*)(Ar + k);
        d0 += dot4(x, *(const float4*)(wt + k));
        d1 += dot4(x, *(const float4*)(wt + 512 + k));
      }
#pragma unroll
      for (int off = 1; off < 16; off <<= 1) { d0 += __shfl_xor(d0, off, 64); d1 += __shfl_xor(d1, off, 64); }
      if (kp == 0) {
        int brow = b0 + hrow;
        float msk = (tp < lengths[brow]) ? 1.0f : 0.0f;
        float* o = out + OUT_TC + ((unsigned)brow * 128 + tp) * 24 + 2 * s;
        o[0] = sigm(d0 + b_tc[2 * s]) * msk;
        o[1] = sigm(d1 + b_tc[2 * s + 1]) * msk;
      }
    } else if (s == 15) {
      if (kp == 0) {
        int brow = b0 + hrow;
        float msk = (tp < lengths[brow]) ? 1.0f : 0.0f;
        out[OUT_TCAT + ((unsigned)brow * 128 + tp) * 22 + 6]  = irr_l[hrow][0] * msk;
        out[OUT_TCAT + ((unsigned)brow * 128 + tp) * 22 + 17] = irr_l[hrow][1] * msk;
        out[OUT_VM + (unsigned)brow * 128 + tp] = msk;
        out[OUT_VT + (unsigned)brow * 128 + tp] = tsp;
      }
    } else {
      const int w = (s == 12) ? 6 : (s == 13) ? 10 : 4;
      const float* WT = ws + ((s == 12) ? OFF_HWT0 : (s == 13) ? OFF_HWT2 : OFF_HWT4);
      const float* bt = (s == 12) ? b_tcat0 : (s == 13) ? b_tcat2 : b_tcat4;
      const float* ut = (s == 12) ? u_t0 : (s == 13) ? u_t2 : u_t4;
      const int cbase = (s == 12) ? 0 : (s == 13) ? 7 : 18;
      float lg[10];
#pragma unroll
      for (int c = 0; c < 10; ++c) lg[c] = 0.0f;
#pragma unroll
      for (int i = 0; i < 8; ++i) {
        int k = kp * 4 + 64 * i;
        float4 x = *(const float4*)(Ar + k);
        for (int c = 0; c < w; ++c)
          lg[c] += dot4(x, *(const float4*)(WT + (unsigned)c * 512 + k));
      }
      for (int c = 0; c < w; ++c) {
#pragma unroll
        for (int off = 1; off < 16; off <<= 1) lg[c] += __shfl_xor(lg[c], off, 64);
      }
      if (kp == 0) {
        int brow = b0 + hrow;
        float msk = (tp < lengths[brow]) ? 1.0f : 0.0f;
        float e[10], mx = -1e30f;
        for (int c = 0; c < w; ++c) {
          float uu = ut[((unsigned)tp * 512 + brow) * (unsigned)w + c];
          e[c] = lg[c] + bt[c] + gumb(uu); mx = fmaxf(mx, e[c]);
        }
        float sum = 0.0f;
        for (int c = 0; c < w; ++c) { e[c] = expf(e[c] - mx); sum += e[c]; }
        float inv = 1.0f / sum;
        float* o = out + OUT_TCAT + ((unsigned)brow * 128 + tp) * 22 + cbase;
        for (int c = 0; c < w; ++c) o[c] = e[c] * inv * msk;
      }
    }
    __syncthreads();   // irr_l visible before cell0
  };

  for (int t = 0; t < 128; ++t) {
    const float tsv = (float)t * (1.0f / 127.0f);

    // ---- phase 1: gh0 = h0_prev@Whh0 ; gi0 = precomp + zt@Wtop + ts + irr ----
    float accH[4][3] = {};
    gemmKS(A0, WpA, accH);                 // A0 = h0_prev (staged prev step)
    if (t > 0) {
      stage_finish(A1);                    // h1_new(t-1) -> A1
      do_heads(t - 1);                     // reads A1, updates irr_l
    }
    float accI[4][3] = {};
    gemmZ(t, accI);
    reduce2(accH, accI);                   // kh1 -> LDS, sync, kh0 adds

    if (kh == 0) {                         // cell0 in-register; write h0_new
#pragma unroll
      for (int q = 0; q < 4; ++q) {
        int row = rg8 + 8 * q;
        float i0 = irr_l[row][0], i1 = irr_l[row][1];
        float gir = accI[q][0] + g0s[q][0] + tsv * wts0 + i0 * wi00 + i1 * wi10;
        float giz = accI[q][1] + g0s[q][1] + tsv * wts1 + i0 * wi01 + i1 * wi11;
        float gin = accI[q][2] + g0s[q][2] + tsv * wts2 + i0 * wi02 + i1 * wi12;
        float rr = sigm(gir + accH[q][0] + bh0r);
        float zz = sigm(giz + accH[q][1] + bh0z);
        float nn = tanhf(gin + rr * (accH[q][2] + bh0n));
        float hp = A0[row * AS + jglob];
        astore(h0x + (unsigned)(b0 + row) * 512 + jglob, (1.0f - zz) * nn + zz * hp);
      }
    }

    // gh1 = h1_prev@Whh1 before the barrier (absorbs inter-wg skew)
    float accH2[4][3] = {};
    gemmKS(A1, WpH, accH2);
    gbar();

    // ---- phase 2: gi1 = h0_new@Wih1 ; cell1 ----
    stage_issue(h0x + b0 * 512);
    stage_finish(A0);                      // h0_new -> A0 (= next step's h0_prev)
    float accI2[4][3] = {};
    gemmKS(A0, WpI, accI2);
    reduce2(accH2, accI2);

    if (kh == 0) {
#pragma unroll
      for (int q = 0; q < 4; ++q) {
        int row = rg8 + 8 * q;
        float rr = sigm(accI2[q][0] + bi1r + accH2[q][0] + bh1r);
        float zz = sigm(accI2[q][1] + bi1z + accH2[q][1] + bh1z);
        float nn = tanhf(accI2[q][2] + bi1n + rr * (accH2[q][2] + bh1n));
        float hp = A1[row * AS + jglob];
        astore(h1x + (unsigned)(b0 + row) * 512 + jglob, (1.0f - zz) * nn + zz * hp);
      }
    }
    gbar();

    stage_issue(h1x + b0 * 512);           // drained at next step top
  }
  stage_finish(A1);
  do_heads(127);
}

// ---------------- launcher ----------------
extern "C" void kernel_launch(void* const* d_in, const int* in_sizes, int n_in,
                              void* d_out, int out_size, void* d_ws, size_t ws_size,
                              hipStream_t stream) {
  const float* z_static   = (const float*)d_in[0];
  const float* z_temporal = (const float*)d_in[1];
  const int*   lengths    = (const int*)d_in[2];
  const float* Ws1 = (const float*)d_in[3];
  const float* bs1 = (const float*)d_in[4];
  const float* Ws2 = (const float*)d_in[5];
  const float* bs2 = (const float*)d_in[6];
  const float* W_sc = (const float*)d_in[7];
  const float* b_sc = (const float*)d_in[8];
  const float* W_cat0 = (const float*)d_in[9];
  const float* b_cat0 = (const float*)d_in[10];
  const float* W_cat1 = (const float*)d_in[11];
  const float* b_cat1 = (const float*)d_in[12];
  const float* W_cat2 = (const float*)d_in[13];
  const float* b_cat2 = (const float*)d_in[14];
  const float* W_irr = (const float*)d_in[15];
  const float* b_irr = (const float*)d_in[16];
  const float* Wih0 = (const float*)d_in[17];
  const float* Whh0 = (const float*)d_in[18];
  const float* bih0 = (const float*)d_in[19];
  const float* bhh0 = (const float*)d_in[20];
  const float* Wih1 = (const float*)d_in[21];
  const float* Whh1 = (const float*)d_in[22];
  const float* bih1 = (const float*)d_in[23];
  const float* bhh1 = (const float*)d_in[24];
  const float* W_tc = (const float*)d_in[25];
  const float* b_tc = (const float*)d_in[26];
  const float* W_tcat0 = (const float*)d_in[27];
  const float* b_tcat0 = (const float*)d_in[28];
  const float* W_tcat2 = (const float*)d_in[29];
  const float* b_tcat2 = (const float*)d_in[30];
  const float* W_tcat4 = (const float*)d_in[31];
  const float* b_tcat4 = (const float*)d_in[32];
  const float* W_hz = (const float*)d_in[33];
  const float* b_hz = (const float*)d_in[34];
  const float* u_sc0 = (const float*)d_in[35];
  const float* u_sc1 = (const float*)d_in[36];
  const float* u_sc2 = (const float*)d_in[37];
  const float* u_irr = (const float*)d_in[38];
  const float* u_t0 = (const float*)d_in[39];
  const float* u_t2 = (const float*)d_in[40];
  const float* u_t4 = (const float*)d_in[41];
  const float* u_bern = (const float*)d_in[42];

  float* ws = (float*)d_ws;
  float* out = (float*)d_out;

  hipMemsetAsync((void*)(ws + OFF_CTR), 0, (size_t)(OFF_END - OFF_CTR) * sizeof(float), stream);

  pack_kernel<<<12783, 256, 0, stream>>>(Wih0, Whh0, Wih1, Whh1,
      W_tc, W_hz, W_tcat0, W_tcat2, W_tcat4, ws);
  mlp_kernel<128><<<128, 256, 0, stream>>>(z_static, Ws1, bs1, ws + OFF_HID);
  mlp_kernel<512><<<128, 256, 0, stream>>>(ws + OFF_HID, Ws2, bs2, ws + OFF_BASE);
  static_heads_kernel<<<512, 64, 0, stream>>>(ws + OFF_BASE, W_sc, b_sc,
      W_cat0, b_cat0, W_cat1, b_cat1, W_cat2, b_cat2, W_irr, b_irr,
      u_sc0, u_sc1, u_sc2, u_irr, out, ws + OFF_IRR0);
  gi0_kernel<<<128, 256, 0, stream>>>(ws + OFF_BASE, ws + OFF_WMIDP, bih0, ws + OFF_GI0S);
  recurrence_kernel<<<256, 512, 0, stream>>>(ws, z_temporal, lengths,
      bhh0, bih1, bhh1, b_tc, b_hz, b_tcat0, b_tcat2, b_tcat4,
      u_t0, u_t2, u_t4, u_bern, out);
}

// Round 6
// 13710.817 us; speedup vs baseline: 1.8898x; 1.0654x over previous
//
#include <hip/hip_runtime.h>

// ---------------- problem constants ----------------
// B=512, T=128, H=512, ZT=64, GRU_IN=579
// 256 wgs = 16 groups (32 batch rows) x 16 slices (32 hidden units = 96 gate cols)
// block = 1024 threads = 16 waves = kh(2) x cq(4) x rh(2 row-halves) -> 4 waves/SIMD.
// lane: u8 = lane&7 (unit within quarter), rg8 = lane>>3; lane owns unit 8cq+u8,
// rows {16rh+rg8, 16rh+rg8+8}; acc[2][3]. kh=1 waves write partials to LDS,
// kh=0 waves add + compute the GRU cell in-register.
// B gate-major k-tiled, partitioned over (kh,cq); rh twins share the B stream (L1).

// ---- ws layout (float element offsets) ----
#define OFF_HID    0u        // [512][512]
#define OFF_BASE   262144u   // [512][512] baseline
#define OFF_WHH0P  524288u   // [16][128 k4][3 gate][32 u][4 ki] Whh0
#define OFF_WIH1P  1310720u  // same, Wih1
#define OFF_WHH1P  2097152u  // same, Whh1
#define OFF_WMIDP  2883584u  // [16][96][512] Wih0 rows 64..575 (for gi0_kernel)
#define OFF_WTOPP  3670016u  // [16][16 k4][3][32][4] Wih0 rows 0..63
#define OFF_WTS    3768320u  // [16][96] Wih0 row 576 (c = 3u+gate)
#define OFF_WIRR   3769856u  // [16][2][96] Wih0 rows 577,578
#define OFF_GI0S   3772928u  // [16][512][96] baseline@Wmid + bih0
#define OFF_H0X    4559360u  // [512][512] h0 exchange
#define OFF_H1X    4821504u  // [512][512] h1 exchange
#define OFF_HWTC   5083648u  // [24][512] W_tc^T
#define OFF_HWHZ   5095936u  // [2][516]  W_hz rows (col 512 = t coef, pad)
#define OFF_HWT0   5097088u  // [6][512]  W_tcat0^T
#define OFF_HWT2   5100160u  // [10][512] W_tcat2^T
#define OFF_HWT4   5105280u  // [4][512]  W_tcat4^T
#define OFF_IRR0   5107328u  // [512][2]
#define OFF_CTR    5108352u  // 16 groups x 32 u32 barrier counters
#define OFF_END    5108864u

// ---- out layout (flat concat, reference return order) ----
#define OUT_SC   0u
#define OUT_SCAT 8192u
#define OUT_TC   20992u
#define OUT_TCAT 1593856u
#define OUT_VM   3035648u
#define OUT_VT   3101184u

#define AS 516   // A row stride (pad 4)
#define RS 97    // partial-buffer row stride

__device__ __forceinline__ float sigm(float x) { return 1.0f / (1.0f + expf(-x)); }
__device__ __forceinline__ float gumb(float u) { return -logf(-logf(u + 1e-10f) + 1e-10f); }
__device__ __forceinline__ float dot4(float4 a, float4 b) {
  return fmaf(a.x, b.x, fmaf(a.y, b.y, fmaf(a.z, b.z, a.w * b.w)));
}
__device__ __forceinline__ void astore(float* p, float v) {
  __hip_atomic_store(p, v, __ATOMIC_RELAXED, __HIP_MEMORY_SCOPE_AGENT);
}

// ---------------- weight packing ----------------
__global__ __launch_bounds__(256) void pack_kernel(
    const float* __restrict__ Wih0, const float* __restrict__ Whh0,
    const float* __restrict__ Wih1, const float* __restrict__ Whh1,
    const float* __restrict__ W_tc, const float* __restrict__ W_hz,
    const float* __restrict__ W_tcat0, const float* __restrict__ W_tcat2,
    const float* __restrict__ W_tcat4, float* __restrict__ ws) {
  int idx = blockIdx.x * 256 + threadIdx.x;
  if (idx < 3145728) {
    int m = idx / 786432, r = idx % 786432;
    int s = r / 49152, t = r % 49152;
    if (m < 3) {
      int k4 = t / 384, rem = t % 384;
      int j = rem >> 7, u = (rem >> 2) & 31, ki = rem & 3;
      int k = 4 * k4 + ki;
      int col = j * 512 + s * 32 + u;
      const float* M = (m == 0) ? Whh0 : (m == 1) ? Wih1 : Whh1;
      unsigned dst = (m == 0) ? OFF_WHH0P : (m == 1) ? OFF_WIH1P : OFF_WHH1P;
      ws[dst + (unsigned)r] = M[k * 1536 + col];
    } else {
      int c = t / 512, k = t % 512;
      int col = (c % 3) * 512 + s * 32 + c / 3;
      ws[OFF_WMIDP + (unsigned)r] = Wih0[(64 + k) * 1536 + col];
    }
    return;
  }
  idx -= 3145728;
  if (idx < 98304) {
    int s = idx / 6144, t = idx % 6144;
    int k4 = t / 384, rem = t % 384;
    int j = rem >> 7, u = (rem >> 2) & 31, ki = rem & 3;
    int k = 4 * k4 + ki;
    int col = j * 512 + s * 32 + u;
    ws[OFF_WTOPP + (unsigned)idx] = Wih0[k * 1536 + col];
    return;
  }
  idx -= 98304;
  if (idx < 1536) {
    int s = idx / 96, c = idx % 96;
    ws[OFF_WTS + (unsigned)idx] = Wih0[576 * 1536 + (c % 3) * 512 + s * 32 + (c / 3)];
    return;
  }
  idx -= 1536;
  if (idx < 3072) {
    int s = idx / 192, m = (idx % 192) / 96, c = idx % 96;
    ws[OFF_WIRR + (unsigned)idx] = Wih0[(577 + m) * 1536 + (c % 3) * 512 + s * 32 + (c / 3)];
    return;
  }
  idx -= 3072;
  if (idx < 12288) { int c = idx / 512, k = idx % 512; ws[OFF_HWTC + (unsigned)idx] = W_tc[k * 24 + c]; return; }
  idx -= 12288;
  if (idx < 1032) {
    int c = idx / 516, j = idx % 516;
    ws[OFF_HWHZ + (unsigned)idx] = (j < 513) ? W_hz[c * 513 + j] : 0.0f;
    return;
  }
  idx -= 1032;
  if (idx < 3072) { int c = idx / 512, k = idx % 512; ws[OFF_HWT0 + (unsigned)idx] = W_tcat0[k * 6 + c]; return; }
  idx -= 3072;
  if (idx < 5120) { int c = idx / 512, k = idx % 512; ws[OFF_HWT2 + (unsigned)idx] = W_tcat2[k * 10 + c]; return; }
  idx -= 5120;
  if (idx < 2048) { int c = idx / 512, k = idx % 512; ws[OFF_HWT4 + (unsigned)idx] = W_tcat4[k * 4 + c]; }
}

// ---------------- static MLP ----------------
template <int K>
__global__ __launch_bounds__(256) void mlp_kernel(
    const float* __restrict__ X, const float* __restrict__ Wm,
    const float* __restrict__ bias, float* __restrict__ Y) {
  __shared__ float Xs[4][K];
  const int rt = blockIdx.x, tid = threadIdx.x;
  for (int i = tid; i < 4 * K; i += 256) Xs[i / K][i % K] = X[(rt * 4 + i / K) * K + (i % K)];
  __syncthreads();
  float acc[4][2] = {};
  const int c0 = tid, c1 = tid + 256;
  for (int k = 0; k < K; ++k) {
    float w0 = Wm[k * 512 + c0], w1 = Wm[k * 512 + c1];
#pragma unroll
    for (int r = 0; r < 4; ++r) {
      acc[r][0] = fmaf(Xs[r][k], w0, acc[r][0]);
      acc[r][1] = fmaf(Xs[r][k], w1, acc[r][1]);
    }
  }
#pragma unroll
  for (int r = 0; r < 4; ++r) {
    Y[(rt * 4 + r) * 512 + c0] = fmaxf(acc[r][0] + bias[c0], 0.0f);
    Y[(rt * 4 + r) * 512 + c1] = fmaxf(acc[r][1] + bias[c1], 0.0f);
  }
}

// ---------------- gi0 static part ----------------
__global__ __launch_bounds__(256) void gi0_kernel(
    const float* __restrict__ baseline, const float* __restrict__ WmidP,
    const float* __restrict__ bih0, float* __restrict__ gi0s) {
  __shared__ float As[64][128];
  __shared__ float Bs[96][129];
  const int s = blockIdx.x >> 3, rt = blockIdx.x & 7;
  const int tid = threadIdx.x, cg = tid & 31, rg = tid >> 5;
  float acc[8][3] = {};
  for (int kc = 0; kc < 4; ++kc) {
    for (int i = tid; i < 2048; i += 256) {
      int r = i >> 5, k4 = (i & 31) << 2;
      *(float4*)&As[r][k4] = *(const float4*)&baseline[(rt * 64 + r) * 512 + kc * 128 + k4];
    }
    for (int i = tid; i < 3072; i += 256) {
      int c = i >> 5, k4 = (i & 31) << 2;
      float4 v = *(const float4*)&WmidP[((unsigned)s * 96 + c) * 512 + kc * 128 + k4];
      Bs[c][k4] = v.x; Bs[c][k4 + 1] = v.y; Bs[c][k4 + 2] = v.z; Bs[c][k4 + 3] = v.w;
    }
    __syncthreads();
    for (int kk = 0; kk < 128; ++kk) {
      float b0 = Bs[3 * cg + 0][kk], b1 = Bs[3 * cg + 1][kk], b2 = Bs[3 * cg + 2][kk];
#pragma unroll
      for (int r = 0; r < 8; ++r) {
        float a = As[rg * 8 + r][kk];
        acc[r][0] = fmaf(a, b0, acc[r][0]);
        acc[r][1] = fmaf(a, b1, acc[r][1]);
        acc[r][2] = fmaf(a, b2, acc[r][2]);
      }
    }
    __syncthreads();
  }
#pragma unroll
  for (int r = 0; r < 8; ++r)
#pragma unroll
    for (int j = 0; j < 3; ++j) {
      int c = 3 * cg + j;
      gi0s[((unsigned)s * 512 + rt * 64 + rg * 8 + r) * 96 + c] = acc[r][j] + bih0[j * 512 + s * 32 + cg];
    }
}

// ---------------- static heads ----------------
__device__ void gumbel_write(const float* logits, int w, const float* u, float* dst) {
  float e[12]; float mx = -1e30f;
#pragma unroll
  for (int i = 0; i < 12; ++i) if (i < w) { e[i] = logits[i] + gumb(u[i]); mx = fmaxf(mx, e[i]); }
  float sum = 0.0f;
#pragma unroll
  for (int i = 0; i < 12; ++i) if (i < w) { e[i] = expf(e[i] - mx); sum += e[i]; }
  float inv = 1.0f / sum;
#pragma unroll
  for (int i = 0; i < 12; ++i) if (i < w) dst[i] = e[i] * inv;
}

__global__ __launch_bounds__(64) void static_heads_kernel(
    const float* __restrict__ baseline,
    const float* __restrict__ W_sc, const float* __restrict__ b_sc,
    const float* __restrict__ W_cat0, const float* __restrict__ b_cat0,
    const float* __restrict__ W_cat1, const float* __restrict__ b_cat1,
    const float* __restrict__ W_cat2, const float* __restrict__ b_cat2,
    const float* __restrict__ W_irr, const float* __restrict__ b_irr,
    const float* __restrict__ u_sc0, const float* __restrict__ u_sc1,
    const float* __restrict__ u_sc2, const float* __restrict__ u_irr,
    float* __restrict__ out, float* __restrict__ irr0buf) {
  const int b = blockIdx.x, tid = threadIdx.x;
  __shared__ float br[512];
  __shared__ float dots[48];
  for (int i = tid; i < 512; i += 64) br[i] = baseline[b * 512 + i];
  __syncthreads();
  if (tid < 45) {
    float d = 0.0f;
    if (tid < 16) { for (int k = 0; k < 512; ++k) d = fmaf(br[k], W_sc[k * 16 + tid], d); d += b_sc[tid]; }
    else if (tid < 24) { int c = tid - 16; for (int k = 0; k < 512; ++k) d = fmaf(br[k], W_cat0[k * 8 + c], d); d += b_cat0[c]; }
    else if (tid < 29) { int c = tid - 24; for (int k = 0; k < 512; ++k) d = fmaf(br[k], W_cat1[k * 5 + c], d); d += b_cat1[c]; }
    else if (tid < 41) { int c = tid - 29; for (int k = 0; k < 512; ++k) d = fmaf(br[k], W_cat2[k * 12 + c], d); d += b_cat2[c]; }
    else { int i = tid - 41, j = i >> 1, cls = i & 1;
           for (int k = 0; k < 512; ++k) d = fmaf(br[k], W_irr[j * 1024 + k * 2 + cls], d);
           d += b_irr[j * 2 + cls]; }
    dots[tid] = d;
  }
  __syncthreads();
  if (tid < 16) out[OUT_SC + b * 16 + tid] = sigm(dots[tid]);
  else if (tid == 16) gumbel_write(&dots[16], 8,  u_sc0 + b * 8,  out + OUT_SCAT + b * 25 + 0);
  else if (tid == 17) gumbel_write(&dots[24], 5,  u_sc1 + b * 5,  out + OUT_SCAT + b * 25 + 8);
  else if (tid == 18) gumbel_write(&dots[29], 12, u_sc2 + b * 12, out + OUT_SCAT + b * 25 + 13);
  else if (tid == 19 || tid == 20) {
    int j = tid - 19;
    float e0 = dots[41 + 2 * j] + gumb(u_irr[j * 1024 + b * 2 + 0]);
    float e1 = dots[42 + 2 * j] + gumb(u_irr[j * 1024 + b * 2 + 1]);
    float mx = fmaxf(e0, e1);
    float x0 = expf(e0 - mx), x1 = expf(e1 - mx);
    irr0buf[b * 2 + j] = x1 / (x0 + x1);
  }
}

// ---------------- persistent recurrence kernel ----------------
__global__ __launch_bounds__(1024, 4) void recurrence_kernel(
    float* ws, const float* __restrict__ z_temporal, const int* __restrict__ lengths,
    const float* __restrict__ bhh0, const float* __restrict__ bih1, const float* __restrict__ bhh1,
    const float* __restrict__ b_tc, const float* __restrict__ b_hz,
    const float* __restrict__ b_tcat0, const float* __restrict__ b_tcat2,
    const float* __restrict__ b_tcat4,
    const float* __restrict__ u_t0, const float* __restrict__ u_t2,
    const float* __restrict__ u_t4, const float* __restrict__ u_bern,
    float* __restrict__ out) {
  const int tid = threadIdx.x;
  const int s = blockIdx.x & 15;   // slice -> XCD-pinned (round-robin dispatch)
  const int g = blockIdx.x >> 4;   // batch group
  const int b0 = g * 32;
  // gemm/cell role: 16 waves = kh(2) x cq(4) x rh(2)
  const int lane = tid & 63, wv = tid >> 6;
  const int kh = wv >> 3;          // k-half [256kh, 256kh+256)
  const int cq = (wv >> 1) & 3;    // col quarter: units [8cq, 8cq+8)
  const int rh = wv & 1;           // row half: rows [16rh, 16rh+16)
  const int u8 = lane & 7;
  const int rg8 = lane >> 3;
  const int unit = 8 * cq + u8;    // unit within slice
  const int jglob = s * 32 + unit;
  const int row0 = 16 * rh + rg8;  // lane's rows: row0, row0+8
  // heads role: 32 rows x 32 k-lanes
  const int hrow = tid >> 5, kp = tid & 31;

  __shared__ __align__(16) float A0[32 * AS];      // staged h0 (pad-4 rows)
  __shared__ __align__(16) float A1[32 * AS];      // staged h1
  __shared__ __align__(16) float Rbuf[2 * 32 * RS];// kh=1 partials (2 gemms)
  __shared__ float irr_l[32][2];

  float* h0x = ws + OFF_H0X;
  float* h1x = ws + OFF_H1X;
  unsigned* ctr = ((unsigned*)(ws + OFF_CTR)) + g * 32;

  const float* WpA = ws + OFF_WHH0P + (unsigned)s * 49152;
  const float* WpI = ws + OFF_WIH1P + (unsigned)s * 49152;
  const float* WpH = ws + OFF_WHH1P + (unsigned)s * 49152;
  const float* WpT = ws + OFF_WTOPP + (unsigned)s * 6144;

  // per-lane cell constants (used by kh==0 lanes)
  const int c0u = 3 * unit;
  const float* wtsp  = ws + OFF_WTS + s * 96;
  const float* wirrp = ws + OFF_WIRR + s * 192;
  const float* gi0p  = ws + OFF_GI0S + ((unsigned)s * 512 + b0) * 96;
  float wts0 = wtsp[c0u], wts1 = wtsp[c0u + 1], wts2 = wtsp[c0u + 2];
  float wi00 = wirrp[c0u], wi01 = wirrp[c0u + 1], wi02 = wirrp[c0u + 2];
  float wi10 = wirrp[96 + c0u], wi11 = wirrp[96 + c0u + 1], wi12 = wirrp[96 + c0u + 2];
  float g0s[2][3];
#pragma unroll
  for (int q = 0; q < 2; ++q)
#pragma unroll
    for (int j = 0; j < 3; ++j) g0s[q][j] = gi0p[(row0 + 8 * q) * 96 + c0u + j];
  float bh0r = bhh0[jglob], bh0z = bhh0[512 + jglob], bh0n = bhh0[1024 + jglob];
  float bi1r = bih1[jglob], bi1z = bih1[512 + jglob], bi1n = bih1[1024 + jglob];
  float bh1r = bhh1[jglob], bh1z = bhh1[512 + jglob], bh1n = bhh1[1024 + jglob];
  float bhz0 = b_hz[0], bhz1 = b_hz[1];

  // init
  for (int i = tid; i < 32 * AS; i += 1024) { A0[i] = 0.0f; A1[i] = 0.0f; }
  if (tid < 64) irr_l[tid >> 1][tid & 1] = ws[OFF_IRR0 + (b0 + (tid >> 1)) * 2 + (tid & 1)];
  __syncthreads();

  unsigned bar = 0;
  auto gbar = [&]() {
    __builtin_amdgcn_s_waitcnt(0);
    __syncthreads();
    if (tid == 0) {
      bar += 16;
      __hip_atomic_fetch_add(ctr, 1u, __ATOMIC_RELEASE, __HIP_MEMORY_SCOPE_AGENT);
      while (__hip_atomic_load(ctr, __ATOMIC_RELAXED, __HIP_MEMORY_SCOPE_AGENT) < bar)
        __builtin_amdgcn_s_sleep(1);
    }
    __syncthreads();
    __asm__ __volatile__("" ::: "memory");
  };

  float4 sv[4];  // h staging registers (32 rows x 512 cols / 1024 threads)
  auto stage_issue = [&](const float* src) {
#pragma unroll
    for (int j = 0; j < 4; ++j) {
      int slot = j * 1024 + tid;
      asm volatile("global_load_dwordx4 %0, %1, off sc1"
                   : "=v"(sv[j]) : "v"(src + (slot >> 7) * 512 + ((slot & 127) << 2)));
    }
  };
  auto stage_finish = [&](float* dstLDS) {
    asm volatile("s_waitcnt vmcnt(0)" ::: "memory");
#pragma unroll
    for (int j = 0; j < 4; ++j) {
      int slot = j * 1024 + tid;
      *(float4*)(dstLDS + (slot >> 7) * AS + ((slot & 127) << 2)) = sv[j];
    }
    __syncthreads();
  };

  // K512 gemm, (kh,cq,rh) split: acc[q][gate], rows row0+8q.
  auto gemmKS = [&](const float* A, const float* Bp, float (&acc)[2][3]) {
    const float* bp = Bp + (unsigned)(kh * 64) * 384 + (unsigned)unit * 4;
    const float* ap = A + (unsigned)row0 * AS + kh * 256;
#pragma unroll 4
    for (int k4 = 0; k4 < 64; ++k4) {
      const float* p = bp + (unsigned)k4 * 384;
      float4 w0 = *(const float4*)(p);
      float4 w1 = *(const float4*)(p + 128);
      float4 w2 = *(const float4*)(p + 256);
      float4 av[2];
#pragma unroll
      for (int q = 0; q < 2; ++q) av[q] = *(const float4*)(ap + q * (8 * AS) + k4 * 4);
      const float* w0a = (const float*)&w0;
      const float* w1a = (const float*)&w1;
      const float* w2a = (const float*)&w2;
#pragma unroll
      for (int q = 0; q < 2; ++q) {
        const float* aa = (const float*)&av[q];
#pragma unroll
        for (int i = 0; i < 4; ++i) {
          acc[q][0] = fmaf(aa[i], w0a[i], acc[q][0]);
          acc[q][1] = fmaf(aa[i], w1a[i], acc[q][1]);
          acc[q][2] = fmaf(aa[i], w2a[i], acc[q][2]);
        }
      }
    }
  };

  // z gemm (K=64, k-half 32 per kh), A straight from global
  auto gemmZ = [&](int t, float (&acc)[2][3]) {
    const float* bp = WpT + (unsigned)(kh * 8) * 384 + (unsigned)unit * 4;
#pragma unroll 2
    for (int k4 = 0; k4 < 8; ++k4) {
      const float* p = bp + (unsigned)k4 * 384;
      float4 w0 = *(const float4*)(p);
      float4 w1 = *(const float4*)(p + 128);
      float4 w2 = *(const float4*)(p + 256);
      const float* w0a = (const float*)&w0;
      const float* w1a = (const float*)&w1;
      const float* w2a = (const float*)&w2;
#pragma unroll
      for (int q = 0; q < 2; ++q) {
        int row = b0 + row0 + 8 * q;
        float4 zv = *(const float4*)(z_temporal + ((unsigned)row * 128 + t) * 64 + kh * 32 + k4 * 4);
        const float* aa = (const float*)&zv;
#pragma unroll
        for (int i = 0; i < 4; ++i) {
          acc[q][0] = fmaf(aa[i], w0a[i], acc[q][0]);
          acc[q][1] = fmaf(aa[i], w1a[i], acc[q][1]);
          acc[q][2] = fmaf(aa[i], w2a[i], acc[q][2]);
        }
      }
    }
  };

  // kh=1 writes both gemms' partials; sync; kh=0 adds.
  auto reduce2 = [&](float (&aX)[2][3], float (&aY)[2][3]) {
    if (kh == 1) {
#pragma unroll
      for (int q = 0; q < 2; ++q) {
        int row = row0 + 8 * q;
        float* p0 = Rbuf + row * RS + c0u;
        float* p1 = Rbuf + 32 * RS + row * RS + c0u;
        p0[0] = aX[q][0]; p0[1] = aX[q][1]; p0[2] = aX[q][2];
        p1[0] = aY[q][0]; p1[1] = aY[q][1]; p1[2] = aY[q][2];
      }
    }
    __syncthreads();
    if (kh == 0) {
#pragma unroll
      for (int q = 0; q < 2; ++q) {
        int row = row0 + 8 * q;
        const float* p0 = Rbuf + row * RS + c0u;
        const float* p1 = Rbuf + 32 * RS + row * RS + c0u;
        aX[q][0] += p0[0]; aX[q][1] += p0[1]; aX[q][2] += p0[2];
        aY[q][0] += p1[0]; aY[q][1] += p1[1]; aY[q][2] += p1[2];
      }
    }
  };

  // heads for step tp (reads A1 = h1_new(tp)); updates irr_l; writes outputs
  // layout: hrow (32 rows) x kp (32 lanes, float4 chunks, width-32 shuffles)
  auto do_heads = [&](int tp) {
    const float tsp = (float)tp * (1.0f / 127.0f);
    const float* Ar = A1 + hrow * AS;
    {
      const float* hz = ws + OFF_HWHZ;
      float d0 = 0.0f, d1 = 0.0f;
#pragma unroll
      for (int i = 0; i < 4; ++i) {
        int k = kp * 4 + 128 * i;
        float4 x = *(const float4*)(Ar + k);
        d0 += dot4(x, *(const float4*)(hz + k));
        d1 += dot4(x, *(const float4*)(hz + 516 + k));
      }
#pragma unroll
      for (int off = 1; off < 32; off <<= 1) { d0 += __shfl_xor(d0, off, 32); d1 += __shfl_xor(d1, off, 32); }
      if (kp == 0) {
        float h0v = sigm(d0 + tsp * hz[512] + bhz0);
        float h1v = sigm(d1 + tsp * hz[516 + 512] + bhz1);
        float i0 = irr_l[hrow][0], i1 = irr_l[hrow][1];
        const float* ub = u_bern + ((unsigned)tp * 512 + b0 + hrow) * 2;
        irr_l[hrow][0] = fminf(i0 + ((ub[0] < h0v * (1.0f - i0)) ? 1.0f : 0.0f), 1.0f);
        irr_l[hrow][1] = fminf(i1 + ((ub[1] < h1v * (1.0f - i1)) ? 1.0f : 0.0f), 1.0f);
      }
    }
    if (s < 12) {
      const float* wt = ws + OFF_HWTC + (unsigned)(2 * s) * 512;
      float d0 = 0.0f, d1 = 0.0f;
#pragma unroll
      for (int i = 0; i < 4; ++i) {
        int k = kp * 4 + 128 * i;
        float4 x = *(const float4*)(Ar + k);
        d0 += dot4(x, *(const float4*)(wt + k));
        d1 += dot4(x, *(const float4*)(wt + 512 + k));
      }
#pragma unroll
      for (int off = 1; off < 32; off <<= 1) { d0 += __shfl_xor(d0, off, 32); d1 += __shfl_xor(d1, off, 32); }
      if (kp == 0) {
        int brow = b0 + hrow;
        float msk = (tp < lengths[brow]) ? 1.0f : 0.0f;
        float* o = out + OUT_TC + ((unsigned)brow * 128 + tp) * 24 + 2 * s;
        o[0] = sigm(d0 + b_tc[2 * s]) * msk;
        o[1] = sigm(d1 + b_tc[2 * s + 1]) * msk;
      }
    } else if (s == 15) {
      if (kp == 0) {
        int brow = b0 + hrow;
        float msk = (tp < lengths[brow]) ? 1.0f : 0.0f;
        out[OUT_TCAT + ((unsigned)brow * 128 + tp) * 22 + 6]  = irr_l[hrow][0] * msk;
        out[OUT_TCAT + ((unsigned)brow * 128 + tp) * 22 + 17] = irr_l[hrow][1] * msk;
        out[OUT_VM + (unsigned)brow * 128 + tp] = msk;
        out[OUT_VT + (unsigned)brow * 128 + tp] = tsp;
      }
    } else {
      const int w = (s == 12) ? 6 : (s == 13) ? 10 : 4;
      const float* WT = ws + ((s == 12) ? OFF_HWT0 : (s == 13) ? OFF_HWT2 : OFF_HWT4);
      const float* bt = (s == 12) ? b_tcat0 : (s == 13) ? b_tcat2 : b_tcat4;
      const float* ut = (s == 12) ? u_t0 : (s == 13) ? u_t2 : u_t4;
      const int cbase = (s == 12) ? 0 : (s == 13) ? 7 : 18;
      float lg[10];
#pragma unroll
      for (int c = 0; c < 10; ++c) lg[c] = 0.0f;
#pragma unroll
      for (int i = 0; i < 4; ++i) {
        int k = kp * 4 + 128 * i;
        float4 x = *(const float4*)(Ar + k);
        for (int c = 0; c < w; ++c)
          lg[c] += dot4(x, *(const float4*)(WT + (unsigned)c * 512 + k));
      }
      for (int c = 0; c < w; ++c) {
#pragma unroll
        for (int off = 1; off < 32; off <<= 1) lg[c] += __shfl_xor(lg[c], off, 32);
      }
      if (kp == 0) {
        int brow = b0 + hrow;
        float msk = (tp < lengths[brow]) ? 1.0f : 0.0f;
        float e[10], mx = -1e30f;
        for (int c = 0; c < w; ++c) {
          float uu = ut[((unsigned)tp * 512 + brow) * (unsigned)w + c];
          e[c] = lg[c] + bt[c] + gumb(uu); mx = fmaxf(mx, e[c]);
        }
        float sum = 0.0f;
        for (int c = 0; c < w; ++c) { e[c] = expf(e[c] - mx); sum += e[c]; }
        float inv = 1.0f / sum;
        float* o = out + OUT_TCAT + ((unsigned)brow * 128 + tp) * 22 + cbase;
        for (int c = 0; c < w; ++c) o[c] = e[c] * inv * msk;
      }
    }
    __syncthreads();   // irr_l visible before cell0
  };

  for (int t = 0; t < 128; ++t) {
    const float tsv = (float)t * (1.0f / 127.0f);

    // ---- phase 1: gh0 = h0_prev@Whh0 ; gi0 = precomp + zt@Wtop + ts + irr ----
    float accH[2][3] = {};
    gemmKS(A0, WpA, accH);                 // A0 = h0_prev (staged prev step)
    if (t > 0) {
      stage_finish(A1);                    // h1_new(t-1) -> A1
      do_heads(t - 1);                     // reads A1, updates irr_l
    }
    float accI[2][3] = {};
    gemmZ(t, accI);
    reduce2(accH, accI);                   // kh1 -> LDS, sync, kh0 adds

    if (kh == 0) {                         // cell0 in-register; write h0_new
#pragma unroll
      for (int q = 0; q < 2; ++q) {
        int row = row0 + 8 * q;
        float i0 = irr_l[row][0], i1 = irr_l[row][1];
        float gir = accI[q][0] + g0s[q][0] + tsv * wts0 + i0 * wi00 + i1 * wi10;
        float giz = accI[q][1] + g0s[q][1] + tsv * wts1 + i0 * wi01 + i1 * wi11;
        float gin = accI[q][2] + g0s[q][2] + tsv * wts2 + i0 * wi02 + i1 * wi12;
        float rr = sigm(gir + accH[q][0] + bh0r);
        float zz = sigm(giz + accH[q][1] + bh0z);
        float nn = tanhf(gin + rr * (accH[q][2] + bh0n));
        float hp = A0[row * AS + jglob];
        astore(h0x + (unsigned)(b0 + row) * 512 + jglob, (1.0f - zz) * nn + zz * hp);
      }
    }

    // gh1 = h1_prev@Whh1 before the barrier (absorbs inter-wg skew)
    float accH2[2][3] = {};
    gemmKS(A1, WpH, accH2);
    gbar();

    // ---- phase 2: gi1 = h0_new@Wih1 ; cell1 ----
    stage_issue(h0x + b0 * 512);
    stage_finish(A0);                      // h0_new -> A0 (= next step's h0_prev)
    float accI2[2][3] = {};
    gemmKS(A0, WpI, accI2);
    reduce2(accH2, accI2);

    if (kh == 0) {
#pragma unroll
      for (int q = 0; q < 2; ++q) {
        int row = row0 + 8 * q;
        float rr = sigm(accI2[q][0] + bi1r + accH2[q][0] + bh1r);
        float zz = sigm(accI2[q][1] + bi1z + accH2[q][1] + bh1z);
        float nn = tanhf(accI2[q][2] + bi1n + rr * (accH2[q][2] + bh1n));
        float hp = A1[row * AS + jglob];
        astore(h1x + (unsigned)(b0 + row) * 512 + jglob, (1.0f - zz) * nn + zz * hp);
      }
    }
    gbar();

    stage_issue(h1x + b0 * 512);           // drained at next step top
  }
  stage_finish(A1);
  do_heads(127);
}

// ---------------- launcher ----------------
extern "C" void kernel_launch(void* const* d_in, const int* in_sizes, int n_in,
                              void* d_out, int out_size, void* d_ws, size_t ws_size,
                              hipStream_t stream) {
  const float* z_static   = (const float*)d_in[0];
  const float* z_temporal = (const float*)d_in[1];
  const int*   lengths    = (const int*)d_in[2];
  const float* Ws1 = (const float*)d_in[3];
  const float* bs1 = (const float*)d_in[4];
  const float* Ws2 = (const float*)d_in[5];
  const float* bs2 = (const float*)d_in[6];
  const float* W_sc = (const float*)d_in[7];
  const float* b_sc = (const float*)d_in[8];
  const float* W_cat0 = (const float*)d_in[9];
  const float* b_cat0 = (const float*)d_in[10];
  const float* W_cat1 = (const float*)d_in[11];
  const float* b_cat1 = (const float*)d_in[12];
  const float* W_cat2 = (const float*)d_in[13];
  const float* b_cat2 = (const float*)d_in[14];
  const float* W_irr = (const float*)d_in[15];
  const float* b_irr = (const float*)d_in[16];
  const float* Wih0 = (const float*)d_in[17];
  const float* Whh0 = (const float*)d_in[18];
  const float* bih0 = (const float*)d_in[19];
  const float* bhh0 = (const float*)d_in[20];
  const float* Wih1 = (const float*)d_in[21];
  const float* Whh1 = (const float*)d_in[22];
  const float* bih1 = (const float*)d_in[23];
  const float* bhh1 = (const float*)d_in[24];
  const float* W_tc = (const float*)d_in[25];
  const float* b_tc = (const float*)d_in[26];
  const float* W_tcat0 = (const float*)d_in[27];
  const float* b_tcat0 = (const float*)d_in[28];
  const float* W_tcat2 = (const float*)d_in[29];
  const float* b_tcat2 = (const float*)d_in[30];
  const float* W_tcat4 = (const float*)d_in[31];
  const float* b_tcat4 = (const float*)d_in[32];
  const float* W_hz = (const float*)d_in[33];
  const float* b_hz = (const float*)d_in[34];
  const float* u_sc0 = (const float*)d_in[35];
  const float* u_sc1 = (const float*)d_in[36];
  const float* u_sc2 = (const float*)d_in[37];
  const float* u_irr = (const float*)d_in[38];
  const float* u_t0 = (const float*)d_in[39];
  const float* u_t2 = (const float*)d_in[40];
  const float* u_t4 = (const float*)d_in[41];
  const float* u_bern = (const float*)d_in[42];

  float* ws = (float*)d_ws;
  float* out = (float*)d_out;

  hipMemsetAsync((void*)(ws + OFF_CTR), 0, (size_t)(OFF_END - OFF_CTR) * sizeof(float), stream);

  pack_kernel<<<12783, 256, 0, stream>>>(Wih0, Whh0, Wih1, Whh1,
      W_tc, W_hz, W_tcat0, W_tcat2, W_tcat4, ws);
  mlp_kernel<128><<<128, 256, 0, stream>>>(z_static, Ws1, bs1, ws + OFF_HID);
  mlp_kernel<512><<<128, 256, 0, stream>>>(ws + OFF_HID, Ws2, bs2, ws + OFF_BASE);
  static_heads_kernel<<<512, 64, 0, stream>>>(ws + OFF_BASE, W_sc, b_sc,
      W_cat0, b_cat0, W_cat1, b_cat1, W_cat2, b_cat2, W_irr, b_irr,
      u_sc0, u_sc1, u_sc2, u_irr, out, ws + OFF_IRR0);
  gi0_kernel<<<128, 256, 0, stream>>>(ws + OFF_BASE, ws + OFF_WMIDP, bih0, ws + OFF_GI0S);
  recurrence_kernel<<<256, 1024, 0, stream>>>(ws, z_temporal, lengths,
      bhh0, bih1, bhh1, b_tc, b_hz, b_tcat0, b_tcat2, b_tcat4,
      u_t0, u_t2, u_t4, u_bern, out);
}